// Round 1
// baseline (473.909 us; speedup 1.0000x reference)
//
#include <hip/hip_runtime.h>
#include <hip/hip_bf16.h>
#include <cstdint>
#include <cstddef>

// ---------------------------------------------------------------------------
// LSTM cell: ht = sigmoid(o) * tanh(sigmoid(f)*c + sigmoid(i)*sigmoid(c~))
// gates = [prev_state, x] @ [W_fg;W_ig;W_og;W_ol]^T   (M=4096,K=4096,N=8192)
// Strategy: bf16 MFMA GEMM (m97 structure), bf16 gate scratch, fused epilogue.
// ---------------------------------------------------------------------------

typedef __bf16 nbf16;
typedef nbf16 bf16x8 __attribute__((ext_vector_type(8)));
typedef float f32x4 __attribute__((ext_vector_type(4)));

static constexpr int MDIM = 4096;   // batch
static constexpr int NDIM = 8192;   // 4*H
static constexpr int KDIM = 4096;   // H + I
static constexpr int HDIM = 2048;
static constexpr int BM = 128, BN = 128, BK = 64;

__device__ __forceinline__ void async16(void* lds, const void* g) {
    __builtin_amdgcn_global_load_lds(
        (const __attribute__((address_space(1))) void*)g,
        (__attribute__((address_space(3))) void*)lds,
        16, 0, 0);
}

__device__ __forceinline__ float sigmoidf_(float x) {
    return 1.0f / (1.0f + __expf(-x));
}

// ---- concat(prev_state, x) -> bf16 A [MDIM][KDIM] -------------------------
__global__ __launch_bounds__(256) void k_concat_cast(
        const float* __restrict__ prev, const float* __restrict__ x,
        __hip_bfloat16* __restrict__ A) {
    const size_t total8 = (size_t)MDIM * KDIM / 8;
    const size_t stride = (size_t)gridDim.x * blockDim.x;
    for (size_t i = (size_t)blockIdx.x * blockDim.x + threadIdx.x; i < total8;
         i += stride) {
        size_t e = i * 8;
        size_t b = e >> 12;                  // / KDIM
        int k = (int)(e & (KDIM - 1));
        const float* src = (k < HDIM) ? (prev + b * HDIM + k)
                                      : (x + b * HDIM + (k - HDIM));
        float4 v0 = *(const float4*)src;
        float4 v1 = *(const float4*)(src + 4);
        union { __hip_bfloat16 h[8]; int4 q; } u;
        u.h[0] = __float2bfloat16(v0.x); u.h[1] = __float2bfloat16(v0.y);
        u.h[2] = __float2bfloat16(v0.z); u.h[3] = __float2bfloat16(v0.w);
        u.h[4] = __float2bfloat16(v1.x); u.h[5] = __float2bfloat16(v1.y);
        u.h[6] = __float2bfloat16(v1.z); u.h[7] = __float2bfloat16(v1.w);
        *(int4*)(A + e) = u.q;
    }
}

// ---- [W_fg;W_ig;W_og;W_ol] -> bf16 W [NDIM][KDIM] --------------------------
__global__ __launch_bounds__(256) void k_cast_w(
        const float* __restrict__ w0, const float* __restrict__ w1,
        const float* __restrict__ w2, const float* __restrict__ w3,
        __hip_bfloat16* __restrict__ W) {
    const size_t per = (size_t)HDIM * KDIM;          // 2^23
    const size_t total8 = 4 * per / 8;
    const size_t stride = (size_t)gridDim.x * blockDim.x;
    for (size_t i = (size_t)blockIdx.x * blockDim.x + threadIdx.x; i < total8;
         i += stride) {
        size_t e = i * 8;
        int g = (int)(e >> 23);
        size_t rem = e & (per - 1);
        const float* src = (g == 0 ? w0 : g == 1 ? w1 : g == 2 ? w2 : w3) + rem;
        float4 v0 = *(const float4*)src;
        float4 v1 = *(const float4*)(src + 4);
        union { __hip_bfloat16 h[8]; int4 q; } u;
        u.h[0] = __float2bfloat16(v0.x); u.h[1] = __float2bfloat16(v0.y);
        u.h[2] = __float2bfloat16(v0.z); u.h[3] = __float2bfloat16(v0.w);
        u.h[4] = __float2bfloat16(v1.x); u.h[5] = __float2bfloat16(v1.y);
        u.h[6] = __float2bfloat16(v1.z); u.h[7] = __float2bfloat16(v1.w);
        *(int4*)(W + e) = u.q;
    }
}

// ---- GEMM: G[m][n] = sum_k A[m][k]*W[n][k], bf16 in, bf16 out (m97 style) --
__global__ __launch_bounds__(256) void k_gemm(
        const __hip_bfloat16* __restrict__ A, const __hip_bfloat16* __restrict__ W,
        __hip_bfloat16* __restrict__ G) {
    __shared__ nbf16 Al[BM * BK];   // 16 KB, linear [128][64]
    __shared__ nbf16 Bl[BN * BK];   // 16 KB

    // XCD-aware bijective swizzle (nwg = 2048, divisible by 8)
    const int nwg = (MDIM / BM) * (NDIM / BN);       // 2048
    const int bid = blockIdx.x;
    const int swz = (bid & 7) * (nwg >> 3) + (bid >> 3);
    const int mt = swz >> 6;                         // / (NDIM/BN = 64)
    const int nt = swz & 63;
    const int brow = mt * BM, bcol = nt * BN;

    const int tid = threadIdx.x;
    const int wave = tid >> 6;
    const int lane = tid & 63;
    const int wr = wave >> 1, wc = wave & 1;         // 2x2 wave grid, 64x64 each

    f32x4 acc[4][4] = {};

    const char* Abase = (const char*)A + ((size_t)brow * KDIM) * 2;
    const char* Wbase = (const char*)W + ((size_t)bcol * KDIM) * 2;

    for (int kt = 0; kt < KDIM / BK; ++kt) {
        __syncthreads();   // previous tile fully consumed
        const int k0b = kt * BK * 2;  // byte offset in K

        // stage A tile (16 KB): 16 wave-issues of 1024B, linear LDS dest
        #pragma unroll
        for (int j = 0; j < 4; ++j) {
            const int chunk = (j * 4 + wave) * 1024;     // bytes into tile
            const int off = chunk + lane * 16;
            const int rr = off >> 7;                     // 128 B per row
            const int cb = off & 127;
            async16((char*)Al + chunk,
                    Abase + (size_t)rr * (KDIM * 2) + k0b + cb);
        }
        #pragma unroll
        for (int j = 0; j < 4; ++j) {
            const int chunk = (j * 4 + wave) * 1024;
            const int off = chunk + lane * 16;
            const int rr = off >> 7;
            const int cb = off & 127;
            async16((char*)Bl + chunk,
                    Wbase + (size_t)rr * (KDIM * 2) + k0b + cb);
        }
        __syncthreads();   // implicit vmcnt(0) drain -> tile ready

        #pragma unroll
        for (int kk = 0; kk < 2; ++kk) {
            const int ko = kk * 32 + (lane >> 4) * 8;
            bf16x8 af[4], bv[4];
            #pragma unroll
            for (int i = 0; i < 4; ++i)
                af[i] = *(const bf16x8*)&Al[(wr * 64 + i * 16 + (lane & 15)) * BK + ko];
            #pragma unroll
            for (int j = 0; j < 4; ++j)
                bv[j] = *(const bf16x8*)&Bl[(wc * 64 + j * 16 + (lane & 15)) * BK + ko];
            #pragma unroll
            for (int i = 0; i < 4; ++i)
                #pragma unroll
                for (int j = 0; j < 4; ++j)
                    acc[i][j] = __builtin_amdgcn_mfma_f32_16x16x32_bf16(
                        af[i], bv[j], acc[i][j], 0, 0, 0);
        }
    }

    // epilogue: C/D layout col = lane&15, row = (lane>>4)*4 + q  (m89-verified)
    const int c0 = bcol + wc * 64 + (lane & 15);
    const int r0 = brow + wr * 64 + ((lane >> 4) << 2);
    #pragma unroll
    for (int i = 0; i < 4; ++i)
        #pragma unroll
        for (int j = 0; j < 4; ++j)
            #pragma unroll
            for (int q = 0; q < 4; ++q)
                G[(size_t)(r0 + i * 16 + q) * NDIM + (c0 + j * 16)] =
                    __float2bfloat16(acc[i][j][q]);
}

// ---- cell update: ht = sig(o)*tanh(sig(f)*c + sig(i)*sig(c~)) --------------
__global__ __launch_bounds__(256) void k_cell(
        const __hip_bfloat16* __restrict__ G, const float* __restrict__ c,
        float* __restrict__ out) {
    const size_t total8 = (size_t)MDIM * HDIM / 8;
    const size_t stride = (size_t)gridDim.x * blockDim.x;
    for (size_t i = (size_t)blockIdx.x * blockDim.x + threadIdx.x; i < total8;
         i += stride) {
        size_t e = i * 8;
        size_t b = e >> 11;                  // / HDIM
        int h = (int)(e & (HDIM - 1));
        const __hip_bfloat16* gb = G + b * NDIM + h;
        int4 vf = *(const int4*)(gb);
        int4 vi = *(const int4*)(gb + HDIM);
        int4 vc = *(const int4*)(gb + 2 * HDIM);
        int4 vo = *(const int4*)(gb + 3 * HDIM);
        float4 cs0 = *(const float4*)(c + e);
        float4 cs1 = *(const float4*)(c + e + 4);
        const __hip_bfloat16* pf = (const __hip_bfloat16*)&vf;
        const __hip_bfloat16* pi = (const __hip_bfloat16*)&vi;
        const __hip_bfloat16* pc = (const __hip_bfloat16*)&vc;
        const __hip_bfloat16* po = (const __hip_bfloat16*)&vo;
        float cse[8] = {cs0.x, cs0.y, cs0.z, cs0.w, cs1.x, cs1.y, cs1.z, cs1.w};
        float r[8];
        #pragma unroll
        for (int k = 0; k < 8; ++k) {
            float ft = sigmoidf_(__bfloat162float(pf[k]));
            float it = sigmoidf_(__bfloat162float(pi[k]));
            float ctt = sigmoidf_(__bfloat162float(pc[k]));
            float ot = sigmoidf_(__bfloat162float(po[k]));
            float ct = ft * cse[k] + it * ctt;
            r[k] = ot * tanhf(ct);
        }
        float4 o0 = {r[0], r[1], r[2], r[3]};
        float4 o1 = {r[4], r[5], r[6], r[7]};
        *(float4*)(out + e) = o0;
        *(float4*)(out + e + 4) = o1;
    }
}

extern "C" void kernel_launch(void* const* d_in, const int* in_sizes, int n_in,
                              void* d_out, int out_size, void* d_ws, size_t ws_size,
                              hipStream_t stream) {
    const float* x    = (const float*)d_in[0];   // [B, I]
    const float* prev = (const float*)d_in[1];   // [B, H]
    const float* cst  = (const float*)d_in[2];   // [B, H]
    const float* wfg  = (const float*)d_in[3];   // [H, H+I]
    const float* wig  = (const float*)d_in[4];
    const float* wog  = (const float*)d_in[5];
    const float* wol  = (const float*)d_in[6];
    float* out = (float*)d_out;

    char* ws = (char*)d_ws;
    __hip_bfloat16* Abf   = (__hip_bfloat16*)(ws);                         // 32 MB
    __hip_bfloat16* Wbf   = (__hip_bfloat16*)(ws + 33554432);              // 64 MB
    __hip_bfloat16* gates = (__hip_bfloat16*)(ws + 33554432 + 67108864);   // 64 MB

    k_concat_cast<<<2048, 256, 0, stream>>>(prev, x, Abf);
    k_cast_w<<<2048, 256, 0, stream>>>(wfg, wig, wog, wol, Wbf);
    k_gemm<<<2048, 256, 0, stream>>>(Abf, Wbf, gates);
    k_cell<<<2048, 256, 0, stream>>>(gates, cst, out);
}

// Round 2
// 344.671 us; speedup vs baseline: 1.3750x; 1.3750x over previous
//
#include <hip/hip_runtime.h>
#include <hip/hip_bf16.h>
#include <cstdint>
#include <cstddef>

// ---------------------------------------------------------------------------
// LSTM cell: ht = sigmoid(o) * tanh(sigmoid(f)*c + sigmoid(i)*sigmoid(c~))
// gates = [prev_state, x] @ [W_fg;W_ig;W_og;W_ol]^T   (M=4096,K=4096,N=8192)
// GEMM: 256x256 tile, 8-phase counted-vmcnt schedule (m201 template),
// T2 chunk-XOR LDS swizzle, T5 setprio, T1 XCD-bijective block swizzle.
// ---------------------------------------------------------------------------

typedef __bf16 nbf16;
typedef nbf16 bf16x8 __attribute__((ext_vector_type(8)));
typedef float f32x4 __attribute__((ext_vector_type(4)));

static constexpr int MDIM = 4096;   // batch
static constexpr int NDIM = 8192;   // 4*H
static constexpr int KDIM = 4096;   // H + I
static constexpr int HDIM = 2048;
static constexpr int KB   = KDIM * 2;       // row stride in bytes (8192)

#define VMW4  asm volatile("s_waitcnt vmcnt(4)" ::: "memory")
#define VMW0  asm volatile("s_waitcnt vmcnt(0)" ::: "memory")
#define LGKM0 asm volatile("s_waitcnt lgkmcnt(0)" ::: "memory")
#define BAR   __builtin_amdgcn_s_barrier()
#define SB0   __builtin_amdgcn_sched_barrier(0)

__device__ __forceinline__ void async16(void* lds, const void* g) {
    __builtin_amdgcn_global_load_lds(
        (const __attribute__((address_space(1))) void*)g,
        (__attribute__((address_space(3))) void*)lds,
        16, 0, 0);
}

__device__ __forceinline__ float sigmoidf_(float x) {
    return 1.0f / (1.0f + __expf(-x));
}

// Stage one 16KB K-slice half ([256 rows][32 k] bf16) into `slot`.
// LDS dest is linear (HW: wave-uniform base + lane*16); the T2 read-swizzle
// (chunk ^= (row>>1)&3) is realized by inverse-permuting the GLOBAL source.
__device__ __forceinline__ void stage_half(const char* gRow0, int gs, char* slot,
                                           int wave, int lane) {
    const int q    = lane >> 2;                         // row-within-16 group
    const int clog = (lane & 3) ^ ((lane >> 3) & 3);    // logical 16B chunk
    #pragma unroll
    for (int j = 0; j < 2; ++j) {
        const int w = j * 8 + wave;                     // 0..15
        const char* src = gRow0 + (size_t)(w * 16 + q) * KB + gs * 64 + clog * 16;
        async16(slot + w * 1024, src);                  // HW adds lane*16
    }
}

// ---- concat(prev_state, x) -> bf16 A [MDIM][KDIM] -------------------------
__global__ __launch_bounds__(256) void k_concat_cast(
        const float* __restrict__ prev, const float* __restrict__ x,
        __hip_bfloat16* __restrict__ A) {
    const size_t total8 = (size_t)MDIM * KDIM / 8;
    const size_t stride = (size_t)gridDim.x * blockDim.x;
    for (size_t i = (size_t)blockIdx.x * blockDim.x + threadIdx.x; i < total8;
         i += stride) {
        size_t e = i * 8;
        size_t b = e >> 12;
        int k = (int)(e & (KDIM - 1));
        const float* src = (k < HDIM) ? (prev + b * HDIM + k)
                                      : (x + b * HDIM + (k - HDIM));
        float4 v0 = *(const float4*)src;
        float4 v1 = *(const float4*)(src + 4);
        union { __hip_bfloat16 h[8]; int4 q; } u;
        u.h[0] = __float2bfloat16(v0.x); u.h[1] = __float2bfloat16(v0.y);
        u.h[2] = __float2bfloat16(v0.z); u.h[3] = __float2bfloat16(v0.w);
        u.h[4] = __float2bfloat16(v1.x); u.h[5] = __float2bfloat16(v1.y);
        u.h[6] = __float2bfloat16(v1.z); u.h[7] = __float2bfloat16(v1.w);
        *(int4*)(A + e) = u.q;
    }
}

// ---- [W_fg;W_ig;W_og;W_ol] -> bf16 W [NDIM][KDIM] --------------------------
__global__ __launch_bounds__(256) void k_cast_w(
        const float* __restrict__ w0, const float* __restrict__ w1,
        const float* __restrict__ w2, const float* __restrict__ w3,
        __hip_bfloat16* __restrict__ W) {
    const size_t per = (size_t)HDIM * KDIM;          // 2^23
    const size_t total8 = 4 * per / 8;
    const size_t stride = (size_t)gridDim.x * blockDim.x;
    for (size_t i = (size_t)blockIdx.x * blockDim.x + threadIdx.x; i < total8;
         i += stride) {
        size_t e = i * 8;
        int g = (int)(e >> 23);
        size_t rem = e & (per - 1);
        const float* src = (g == 0 ? w0 : g == 1 ? w1 : g == 2 ? w2 : w3) + rem;
        float4 v0 = *(const float4*)src;
        float4 v1 = *(const float4*)(src + 4);
        union { __hip_bfloat16 h[8]; int4 q; } u;
        u.h[0] = __float2bfloat16(v0.x); u.h[1] = __float2bfloat16(v0.y);
        u.h[2] = __float2bfloat16(v0.z); u.h[3] = __float2bfloat16(v0.w);
        u.h[4] = __float2bfloat16(v1.x); u.h[5] = __float2bfloat16(v1.y);
        u.h[6] = __float2bfloat16(v1.z); u.h[7] = __float2bfloat16(v1.w);
        *(int4*)(W + e) = u.q;
    }
}

// ---- GEMM: G[m][n] = sum_k A[m][k]*W[n][k] --------------------------------
// 256x256x(2x32) tiles, 8 waves (2x4), 8-phase counted-vmcnt schedule.
__global__ __launch_bounds__(512, 2) void k_gemm(
        const __hip_bfloat16* __restrict__ A, const __hip_bfloat16* __restrict__ W,
        __hip_bfloat16* __restrict__ G) {
    __shared__ __align__(16) char lds[131072];      // 4 A-slices + 4 B-slices
    char* const ldsA = lds;
    char* const ldsB = lds + 65536;

    // T1: bijective XCD swizzle, nwg = 512 (divisible by 8)
    const int bid = blockIdx.x;
    const int swz = (bid & 7) * 64 + (bid >> 3);
    const int mt = swz >> 5, nt = swz & 31;          // 16 x 32 tile grid
    const int brow = mt * 256, bcol = nt * 256;

    const int tid = threadIdx.x;
    const int wave = tid >> 6, lane = tid & 63;
    const int wr = wave >> 2, wc = wave & 3;         // 2x4 wave grid

    const char* Ab = (const char*)A + (size_t)brow * KB;
    const char* Wb = (const char*)W + (size_t)bcol * KB;

    // T2 read swizzle: stored chunk = logical chunk ^ ((row>>1)&3)
    const int csr = (lane >> 1) & 3;
    const int g   = lane >> 4;
    const int cs  = ((g ^ csr) << 4);
    const int aoff0 = (wr * 128 + (lane & 15)) * 64 + cs;
    const int boff0 = (wc * 64  + (lane & 15)) * 64 + cs;

    f32x4 acc[8][4] = {};
    bf16x8 av[8], bv0, bv1;

    // prologue: stage tile 0 (slices 0,1) -> slots 0,1; order As0,Bs0,As1,Bs1
    stage_half(Ab, 0, ldsA,         wave, lane);
    stage_half(Wb, 0, ldsB,         wave, lane);
    stage_half(Ab, 1, ldsA + 16384, wave, lane);
    stage_half(Wb, 1, ldsB + 16384, wave, lane);

    for (int kt = 0; kt < 63; ++kt) {
        const char* pa0 = ldsA + ((2 * kt)     & 3) * 16384;
        const char* pa1 = ldsA + ((2 * kt + 1) & 3) * 16384;
        const char* pb0 = ldsB + ((2 * kt)     & 3) * 16384;
        const char* pb1 = ldsB + ((2 * kt + 1) & 3) * 16384;
        char* ta0 = ldsA + ((2 * kt + 2) & 3) * 16384;
        char* tb0 = ldsB + ((2 * kt + 2) & 3) * 16384;
        char* ta1 = ldsA + ((2 * kt + 3) & 3) * 16384;
        char* tb1 = ldsB + ((2 * kt + 3) & 3) * 16384;
        const int gs = 2 * kt + 2;                   // next tile's first slice

        // -- phase 0: A(s0) frags + B(s0) ni{0,1}; stage A(next,s0)
        VMW4; BAR; SB0;
        #pragma unroll
        for (int mi = 0; mi < 8; ++mi)
            av[mi] = *(const bf16x8*)(pa0 + aoff0 + mi * 1024);
        bv0 = *(const bf16x8*)(pb0 + boff0);
        bv1 = *(const bf16x8*)(pb0 + boff0 + 1024);
        stage_half(Ab, gs, ta0, wave, lane);
        SB0; BAR; LGKM0; SB0;
        __builtin_amdgcn_s_setprio(1);
        #pragma unroll
        for (int mi = 0; mi < 8; ++mi) {
            acc[mi][0] = __builtin_amdgcn_mfma_f32_16x16x32_bf16(av[mi], bv0, acc[mi][0], 0, 0, 0);
            acc[mi][1] = __builtin_amdgcn_mfma_f32_16x16x32_bf16(av[mi], bv1, acc[mi][1], 0, 0, 0);
        }
        __builtin_amdgcn_s_setprio(0);

        // -- phase 1: B(s0) ni{2,3}; stage B(next,s0)
        BAR; SB0;
        bv0 = *(const bf16x8*)(pb0 + boff0 + 2048);
        bv1 = *(const bf16x8*)(pb0 + boff0 + 3072);
        stage_half(Wb, gs, tb0, wave, lane);
        SB0; BAR; LGKM0; SB0;
        __builtin_amdgcn_s_setprio(1);
        #pragma unroll
        for (int mi = 0; mi < 8; ++mi) {
            acc[mi][2] = __builtin_amdgcn_mfma_f32_16x16x32_bf16(av[mi], bv0, acc[mi][2], 0, 0, 0);
            acc[mi][3] = __builtin_amdgcn_mfma_f32_16x16x32_bf16(av[mi], bv1, acc[mi][3], 0, 0, 0);
        }
        __builtin_amdgcn_s_setprio(0);

        // -- phase 2: A(s1) frags + B(s1) ni{2,3}; stage A(next,s1)
        VMW4; BAR; SB0;
        #pragma unroll
        for (int mi = 0; mi < 8; ++mi)
            av[mi] = *(const bf16x8*)(pa1 + aoff0 + mi * 1024);
        bv0 = *(const bf16x8*)(pb1 + boff0 + 2048);
        bv1 = *(const bf16x8*)(pb1 + boff0 + 3072);
        stage_half(Ab, gs + 1, ta1, wave, lane);
        SB0; BAR; LGKM0; SB0;
        __builtin_amdgcn_s_setprio(1);
        #pragma unroll
        for (int mi = 0; mi < 8; ++mi) {
            acc[mi][2] = __builtin_amdgcn_mfma_f32_16x16x32_bf16(av[mi], bv0, acc[mi][2], 0, 0, 0);
            acc[mi][3] = __builtin_amdgcn_mfma_f32_16x16x32_bf16(av[mi], bv1, acc[mi][3], 0, 0, 0);
        }
        __builtin_amdgcn_s_setprio(0);

        // -- phase 3: B(s1) ni{0,1}; stage B(next,s1)
        BAR; SB0;
        bv0 = *(const bf16x8*)(pb1 + boff0);
        bv1 = *(const bf16x8*)(pb1 + boff0 + 1024);
        stage_half(Wb, gs + 1, tb1, wave, lane);
        SB0; BAR; LGKM0; SB0;
        __builtin_amdgcn_s_setprio(1);
        #pragma unroll
        for (int mi = 0; mi < 8; ++mi) {
            acc[mi][0] = __builtin_amdgcn_mfma_f32_16x16x32_bf16(av[mi], bv0, acc[mi][0], 0, 0, 0);
            acc[mi][1] = __builtin_amdgcn_mfma_f32_16x16x32_bf16(av[mi], bv1, acc[mi][1], 0, 0, 0);
        }
        __builtin_amdgcn_s_setprio(0);
    }

    // ---- tail tile kt = 63 (slices in slots 2,3), no staging ----
    {
        const char* pa0 = ldsA + 2 * 16384;
        const char* pa1 = ldsA + 3 * 16384;
        const char* pb0 = ldsB + 2 * 16384;
        const char* pb1 = ldsB + 3 * 16384;

        VMW4; BAR; SB0;
        #pragma unroll
        for (int mi = 0; mi < 8; ++mi)
            av[mi] = *(const bf16x8*)(pa0 + aoff0 + mi * 1024);
        bv0 = *(const bf16x8*)(pb0 + boff0);
        bv1 = *(const bf16x8*)(pb0 + boff0 + 1024);
        #pragma unroll
        for (int mi = 0; mi < 8; ++mi) {
            acc[mi][0] = __builtin_amdgcn_mfma_f32_16x16x32_bf16(av[mi], bv0, acc[mi][0], 0, 0, 0);
            acc[mi][1] = __builtin_amdgcn_mfma_f32_16x16x32_bf16(av[mi], bv1, acc[mi][1], 0, 0, 0);
        }
        bv0 = *(const bf16x8*)(pb0 + boff0 + 2048);
        bv1 = *(const bf16x8*)(pb0 + boff0 + 3072);
        #pragma unroll
        for (int mi = 0; mi < 8; ++mi) {
            acc[mi][2] = __builtin_amdgcn_mfma_f32_16x16x32_bf16(av[mi], bv0, acc[mi][2], 0, 0, 0);
            acc[mi][3] = __builtin_amdgcn_mfma_f32_16x16x32_bf16(av[mi], bv1, acc[mi][3], 0, 0, 0);
        }
        VMW0; BAR; SB0;
        #pragma unroll
        for (int mi = 0; mi < 8; ++mi)
            av[mi] = *(const bf16x8*)(pa1 + aoff0 + mi * 1024);
        bv0 = *(const bf16x8*)(pb1 + boff0);
        bv1 = *(const bf16x8*)(pb1 + boff0 + 1024);
        #pragma unroll
        for (int mi = 0; mi < 8; ++mi) {
            acc[mi][0] = __builtin_amdgcn_mfma_f32_16x16x32_bf16(av[mi], bv0, acc[mi][0], 0, 0, 0);
            acc[mi][1] = __builtin_amdgcn_mfma_f32_16x16x32_bf16(av[mi], bv1, acc[mi][1], 0, 0, 0);
        }
        bv0 = *(const bf16x8*)(pb1 + boff0 + 2048);
        bv1 = *(const bf16x8*)(pb1 + boff0 + 3072);
        #pragma unroll
        for (int mi = 0; mi < 8; ++mi) {
            acc[mi][2] = __builtin_amdgcn_mfma_f32_16x16x32_bf16(av[mi], bv0, acc[mi][2], 0, 0, 0);
            acc[mi][3] = __builtin_amdgcn_mfma_f32_16x16x32_bf16(av[mi], bv1, acc[mi][3], 0, 0, 0);
        }
    }

    // ---- epilogue: C/D layout col = lane&15, row = (lane>>4)*4 + q ----
    const int c0 = bcol + wc * 64 + (lane & 15);
    const int r0 = brow + wr * 128 + ((lane >> 4) << 2);
    #pragma unroll
    for (int mi = 0; mi < 8; ++mi)
        #pragma unroll
        for (int ni = 0; ni < 4; ++ni)
            #pragma unroll
            for (int q = 0; q < 4; ++q)
                G[(size_t)(r0 + mi * 16 + q) * NDIM + (c0 + ni * 16)] =
                    __float2bfloat16(acc[mi][ni][q]);
}

// ---- cell update: ht = sig(o)*tanh(sig(f)*c + sig(i)*sig(c~)) --------------
__global__ __launch_bounds__(256) void k_cell(
        const __hip_bfloat16* __restrict__ G, const float* __restrict__ c,
        float* __restrict__ out) {
    const size_t total8 = (size_t)MDIM * HDIM / 8;
    const size_t stride = (size_t)gridDim.x * blockDim.x;
    for (size_t i = (size_t)blockIdx.x * blockDim.x + threadIdx.x; i < total8;
         i += stride) {
        size_t e = i * 8;
        size_t b = e >> 11;
        int h = (int)(e & (HDIM - 1));
        const __hip_bfloat16* gb = G + b * NDIM + h;
        int4 vf = *(const int4*)(gb);
        int4 vi = *(const int4*)(gb + HDIM);
        int4 vc = *(const int4*)(gb + 2 * HDIM);
        int4 vo = *(const int4*)(gb + 3 * HDIM);
        float4 cs0 = *(const float4*)(c + e);
        float4 cs1 = *(const float4*)(c + e + 4);
        const __hip_bfloat16* pf = (const __hip_bfloat16*)&vf;
        const __hip_bfloat16* pi = (const __hip_bfloat16*)&vi;
        const __hip_bfloat16* pc = (const __hip_bfloat16*)&vc;
        const __hip_bfloat16* po = (const __hip_bfloat16*)&vo;
        float cse[8] = {cs0.x, cs0.y, cs0.z, cs0.w, cs1.x, cs1.y, cs1.z, cs1.w};
        float r[8];
        #pragma unroll
        for (int k = 0; k < 8; ++k) {
            float ft = sigmoidf_(__bfloat162float(pf[k]));
            float it = sigmoidf_(__bfloat162float(pi[k]));
            float ctt = sigmoidf_(__bfloat162float(pc[k]));
            float ot = sigmoidf_(__bfloat162float(po[k]));
            float ct = ft * cse[k] + it * ctt;
            r[k] = ot * tanhf(ct);
        }
        float4 o0 = {r[0], r[1], r[2], r[3]};
        float4 o1 = {r[4], r[5], r[6], r[7]};
        *(float4*)(out + e) = o0;
        *(float4*)(out + e + 4) = o1;
    }
}

extern "C" void kernel_launch(void* const* d_in, const int* in_sizes, int n_in,
                              void* d_out, int out_size, void* d_ws, size_t ws_size,
                              hipStream_t stream) {
    const float* x    = (const float*)d_in[0];   // [B, I]
    const float* prev = (const float*)d_in[1];   // [B, H]
    const float* cst  = (const float*)d_in[2];   // [B, H]
    const float* wfg  = (const float*)d_in[3];   // [H, H+I]
    const float* wig  = (const float*)d_in[4];
    const float* wog  = (const float*)d_in[5];
    const float* wol  = (const float*)d_in[6];
    float* out = (float*)d_out;

    char* ws = (char*)d_ws;
    __hip_bfloat16* Abf   = (__hip_bfloat16*)(ws);                         // 32 MB
    __hip_bfloat16* Wbf   = (__hip_bfloat16*)(ws + 33554432);              // 64 MB
    __hip_bfloat16* gates = (__hip_bfloat16*)(ws + 33554432 + 67108864);   // 64 MB

    k_concat_cast<<<2048, 256, 0, stream>>>(prev, x, Abf);
    k_cast_w<<<2048, 256, 0, stream>>>(wfg, wig, wog, wol, Wbf);
    k_gemm<<<512, 512, 0, stream>>>(Abf, Wbf, gates);
    k_cell<<<2048, 256, 0, stream>>>(gates, cst, out);
}

// Round 3
// 334.885 us; speedup vs baseline: 1.4151x; 1.0292x over previous
//
#include <hip/hip_runtime.h>
#include <hip/hip_bf16.h>
#include <cstdint>
#include <cstddef>

// ---------------------------------------------------------------------------
// LSTM cell: ht = sigmoid(o) * tanh(sigmoid(f)*c + sigmoid(i)*sigmoid(c~))
// gates = [prev_state, x] @ [W_fg;W_ig;W_og;W_ol]^T   (M=4096,K=4096,N=8192)
// GEMM: 256x256 tile, BK=32, 4-slot LDS ring, register-level software pipeline
// (LDS reads overlap MFMA), counted vmcnt, 1 barrier/K-tile, LDS-repack epilogue.
// ---------------------------------------------------------------------------

typedef __bf16 nbf16;
typedef nbf16 bf16x8 __attribute__((ext_vector_type(8)));
typedef float f32x4 __attribute__((ext_vector_type(4)));

static constexpr int MDIM = 4096;   // batch
static constexpr int NDIM = 8192;   // 4*H
static constexpr int KDIM = 4096;   // H + I
static constexpr int HDIM = 2048;
static constexpr int KB   = KDIM * 2;       // row stride in bytes

#define VMW4  asm volatile("s_waitcnt vmcnt(4)" ::: "memory")
#define VMW0  asm volatile("s_waitcnt vmcnt(0)" ::: "memory")
#define BAR   __builtin_amdgcn_s_barrier()
#define SB0   __builtin_amdgcn_sched_barrier(0)
#define MF(i,j,A_,B_) acc[i][j] = __builtin_amdgcn_mfma_f32_16x16x32_bf16(A_, B_, acc[i][j], 0, 0, 0)

__device__ __forceinline__ void async16(void* lds, const void* g) {
    __builtin_amdgcn_global_load_lds(
        (const __attribute__((address_space(1))) void*)g,
        (__attribute__((address_space(3))) void*)lds,
        16, 0, 0);
}

__device__ __forceinline__ float sigmoidf_(float x) {
    return 1.0f / (1.0f + __expf(-x));
}

// Stage one 16KB K-slice ([256 rows][32 k] bf16) into `slot` (2 loads/thread).
// Linear LDS dest; T2 read-swizzle realized by inverse-permuting global source.
__device__ __forceinline__ void stage_half(const char* gRow0, int gs, char* slot,
                                           int wave, int lane) {
    const int q    = lane >> 2;
    const int clog = (lane & 3) ^ ((lane >> 3) & 3);
    #pragma unroll
    for (int j = 0; j < 2; ++j) {
        const int w = j * 8 + wave;
        const char* src = gRow0 + (size_t)(w * 16 + q) * KB + gs * 64 + clog * 16;
        async16(slot + w * 1024, src);
    }
}

// ---- concat(prev_state, x) -> bf16 A [MDIM][KDIM] -------------------------
__global__ __launch_bounds__(256) void k_concat_cast(
        const float* __restrict__ prev, const float* __restrict__ x,
        __hip_bfloat16* __restrict__ A) {
    const size_t total8 = (size_t)MDIM * KDIM / 8;
    const size_t stride = (size_t)gridDim.x * blockDim.x;
    for (size_t i = (size_t)blockIdx.x * blockDim.x + threadIdx.x; i < total8;
         i += stride) {
        size_t e = i * 8;
        size_t b = e >> 12;
        int k = (int)(e & (KDIM - 1));
        const float* src = (k < HDIM) ? (prev + b * HDIM + k)
                                      : (x + b * HDIM + (k - HDIM));
        float4 v0 = *(const float4*)src;
        float4 v1 = *(const float4*)(src + 4);
        union { __hip_bfloat16 h[8]; int4 q; } u;
        u.h[0] = __float2bfloat16(v0.x); u.h[1] = __float2bfloat16(v0.y);
        u.h[2] = __float2bfloat16(v0.z); u.h[3] = __float2bfloat16(v0.w);
        u.h[4] = __float2bfloat16(v1.x); u.h[5] = __float2bfloat16(v1.y);
        u.h[6] = __float2bfloat16(v1.z); u.h[7] = __float2bfloat16(v1.w);
        *(int4*)(A + e) = u.q;
    }
}

// ---- [W_fg;W_ig;W_og;W_ol] -> bf16 W [NDIM][KDIM] --------------------------
__global__ __launch_bounds__(256) void k_cast_w(
        const float* __restrict__ w0, const float* __restrict__ w1,
        const float* __restrict__ w2, const float* __restrict__ w3,
        __hip_bfloat16* __restrict__ W) {
    const size_t per = (size_t)HDIM * KDIM;
    const size_t total8 = 4 * per / 8;
    const size_t stride = (size_t)gridDim.x * blockDim.x;
    for (size_t i = (size_t)blockIdx.x * blockDim.x + threadIdx.x; i < total8;
         i += stride) {
        size_t e = i * 8;
        int g = (int)(e >> 23);
        size_t rem = e & (per - 1);
        const float* src = (g == 0 ? w0 : g == 1 ? w1 : g == 2 ? w2 : w3) + rem;
        float4 v0 = *(const float4*)src;
        float4 v1 = *(const float4*)(src + 4);
        union { __hip_bfloat16 h[8]; int4 q; } u;
        u.h[0] = __float2bfloat16(v0.x); u.h[1] = __float2bfloat16(v0.y);
        u.h[2] = __float2bfloat16(v0.z); u.h[3] = __float2bfloat16(v0.w);
        u.h[4] = __float2bfloat16(v1.x); u.h[5] = __float2bfloat16(v1.y);
        u.h[6] = __float2bfloat16(v1.z); u.h[7] = __float2bfloat16(v1.w);
        *(int4*)(W + e) = u.q;
    }
}

// ---- GEMM: G[m][n] = sum_k A[m][k]*W[n][k] --------------------------------
__global__ __launch_bounds__(512, 2) void k_gemm(
        const __hip_bfloat16* __restrict__ A, const __hip_bfloat16* __restrict__ W,
        __hip_bfloat16* __restrict__ G) {
    __shared__ __align__(16) char lds[131072];   // 4 ring slots x (A 16KB + B 16KB)

    const int bid = blockIdx.x;
    const int swz = (bid & 7) * 64 + (bid >> 3);     // T1 bijective XCD swizzle
    const int mt = swz >> 5, nt = swz & 31;
    const int brow = mt * 256, bcol = nt * 256;

    const int tid = threadIdx.x;
    const int wave = tid >> 6, lane = tid & 63;
    const int wr = wave >> 2, wc = wave & 3;         // 2x4 wave grid, 128x64 each

    const char* Ab = (const char*)A + (size_t)brow * KB;
    const char* Wb = (const char*)W + (size_t)bcol * KB;

    // read-side chunk swizzle (matches stage_half's inverse permutation)
    const int cs    = (((lane >> 4) ^ ((lane >> 1) & 3)) << 4);
    const int aoff0 = (wr * 128 + (lane & 15)) * 64 + cs;
    const int boff0 = (wc * 64  + (lane & 15)) * 64 + cs;

    f32x4 acc[8][4] = {};

    // prologue: stage K-tiles 0,1,2 into slots 0,1,2 (12 loads/thread)
    #pragma unroll
    for (int t = 0; t < 3; ++t) {
        char* sA = lds + t * 32768;
        stage_half(Ab, t, sA, wave, lane);
        stage_half(Wb, t, sA + 16384, wave, lane);
    }
    asm volatile("s_waitcnt vmcnt(8)" ::: "memory");   // tile 0 certified
    BAR;

    // setA(0): av0-3 + bv0-3 from slot 0
    bf16x8 a0 = *(const bf16x8*)(lds + aoff0);
    bf16x8 a1 = *(const bf16x8*)(lds + aoff0 + 1024);
    bf16x8 a2 = *(const bf16x8*)(lds + aoff0 + 2048);
    bf16x8 a3 = *(const bf16x8*)(lds + aoff0 + 3072);
    bf16x8 b0 = *(const bf16x8*)(lds + 16384 + boff0);
    bf16x8 b1 = *(const bf16x8*)(lds + 16384 + boff0 + 1024);
    bf16x8 b2 = *(const bf16x8*)(lds + 16384 + boff0 + 2048);
    bf16x8 b3 = *(const bf16x8*)(lds + 16384 + boff0 + 3072);

    for (int t = 0; t < 127; ++t) {
        if (t < 126) { VMW4; } else { VMW0; }   // certify slot (t+1)
        BAR;                                     // all waves certified; slot (t+3)&3 free
        if (t < 125) {
            char* sA = lds + ((t + 3) & 3) * 32768;
            stage_half(Ab, t + 3, sA, wave, lane);
            stage_half(Wb, t + 3, sA + 16384, wave, lane);
        }
        const char* sc = lds + (t & 3) * 32768;
        // setB(t): av4-7 (grinds on LDS pipe during cluster 1)
        bf16x8 a4 = *(const bf16x8*)(sc + aoff0 + 4096);
        bf16x8 a5 = *(const bf16x8*)(sc + aoff0 + 5120);
        bf16x8 a6 = *(const bf16x8*)(sc + aoff0 + 6144);
        bf16x8 a7 = *(const bf16x8*)(sc + aoff0 + 7168);
        SB0;
        __builtin_amdgcn_s_setprio(1);
        MF(0,0,a0,b0); MF(0,1,a0,b1); MF(0,2,a0,b2); MF(0,3,a0,b3);
        MF(1,0,a1,b0); MF(1,1,a1,b1); MF(1,2,a1,b2); MF(1,3,a1,b3);
        MF(2,0,a2,b0); MF(2,1,a2,b1); MF(2,2,a2,b2); MF(2,3,a2,b3);
        MF(3,0,a3,b0); MF(3,1,a3,b1); MF(3,2,a3,b2); MF(3,3,a3,b3);
        __builtin_amdgcn_s_setprio(0);
        SB0;
        // setA(t+1): next tile's av0-3 + bv0-3 (overlaps cluster 2)
        const char* sn = lds + ((t + 1) & 3) * 32768;
        bf16x8 na0 = *(const bf16x8*)(sn + aoff0);
        bf16x8 na1 = *(const bf16x8*)(sn + aoff0 + 1024);
        bf16x8 na2 = *(const bf16x8*)(sn + aoff0 + 2048);
        bf16x8 na3 = *(const bf16x8*)(sn + aoff0 + 3072);
        bf16x8 nb0 = *(const bf16x8*)(sn + 16384 + boff0);
        bf16x8 nb1 = *(const bf16x8*)(sn + 16384 + boff0 + 1024);
        bf16x8 nb2 = *(const bf16x8*)(sn + 16384 + boff0 + 2048);
        bf16x8 nb3 = *(const bf16x8*)(sn + 16384 + boff0 + 3072);
        SB0;
        __builtin_amdgcn_s_setprio(1);
        MF(4,0,a4,b0); MF(4,1,a4,b1); MF(4,2,a4,b2); MF(4,3,a4,b3);
        MF(5,0,a5,b0); MF(5,1,a5,b1); MF(5,2,a5,b2); MF(5,3,a5,b3);
        MF(6,0,a6,b0); MF(6,1,a6,b1); MF(6,2,a6,b2); MF(6,3,a6,b3);
        MF(7,0,a7,b0); MF(7,1,a7,b1); MF(7,2,a7,b2); MF(7,3,a7,b3);
        __builtin_amdgcn_s_setprio(0);
        SB0;
        a0 = na0; a1 = na1; a2 = na2; a3 = na3;
        b0 = nb0; b1 = nb1; b2 = nb2; b3 = nb3;
    }

    // tail K-tile t=127 (slot 3; certified at t=126's VMW0+BAR)
    {
        const char* sc = lds + 3 * 32768;
        bf16x8 a4 = *(const bf16x8*)(sc + aoff0 + 4096);
        bf16x8 a5 = *(const bf16x8*)(sc + aoff0 + 5120);
        bf16x8 a6 = *(const bf16x8*)(sc + aoff0 + 6144);
        bf16x8 a7 = *(const bf16x8*)(sc + aoff0 + 7168);
        MF(0,0,a0,b0); MF(0,1,a0,b1); MF(0,2,a0,b2); MF(0,3,a0,b3);
        MF(1,0,a1,b0); MF(1,1,a1,b1); MF(1,2,a1,b2); MF(1,3,a1,b3);
        MF(2,0,a2,b0); MF(2,1,a2,b1); MF(2,2,a2,b2); MF(2,3,a2,b3);
        MF(3,0,a3,b0); MF(3,1,a3,b1); MF(3,2,a3,b2); MF(3,3,a3,b3);
        MF(4,0,a4,b0); MF(4,1,a4,b1); MF(4,2,a4,b2); MF(4,3,a4,b3);
        MF(5,0,a5,b0); MF(5,1,a5,b1); MF(5,2,a5,b2); MF(5,3,a5,b3);
        MF(6,0,a6,b0); MF(6,1,a6,b1); MF(6,2,a6,b2); MF(6,3,a6,b3);
        MF(7,0,a7,b0); MF(7,1,a7,b1); MF(7,2,a7,b2); MF(7,3,a7,b3);
    }

    // ---- epilogue: repack C tile through LDS, coalesced int4 stores ----
    BAR;   // all waves done reading ring slots
    __hip_bfloat16* cl = (__hip_bfloat16*)lds;   // [256][256] bf16 = 128 KB
    {
        const int rb = wr * 128 + ((lane >> 4) << 2);
        const int cb = wc * 64 + (lane & 15);
        #pragma unroll
        for (int mi = 0; mi < 8; ++mi)
            #pragma unroll
            for (int ni = 0; ni < 4; ++ni)
                #pragma unroll
                for (int q = 0; q < 4; ++q)
                    cl[(rb + mi * 16 + q) * 256 + (cb + ni * 16)] =
                        __float2bfloat16(acc[mi][ni][q]);
    }
    BAR;
    #pragma unroll
    for (int j = 0; j < 16; ++j) {
        const int o = j * 8192 + tid * 16;
        const int r = o >> 9, cb = o & 511;
        *(int4*)((char*)G + ((size_t)(brow + r) * NDIM + bcol) * 2 + cb) =
            *(const int4*)(lds + o);
    }
}

// ---- cell update: ht = sig(o)*tanh(sig(f)*c + sig(i)*sig(c~)) --------------
__global__ __launch_bounds__(256) void k_cell(
        const __hip_bfloat16* __restrict__ G, const float* __restrict__ c,
        float* __restrict__ out) {
    const size_t total8 = (size_t)MDIM * HDIM / 8;
    const size_t stride = (size_t)gridDim.x * blockDim.x;
    for (size_t i = (size_t)blockIdx.x * blockDim.x + threadIdx.x; i < total8;
         i += stride) {
        size_t e = i * 8;
        size_t b = e >> 11;
        int h = (int)(e & (HDIM - 1));
        const __hip_bfloat16* gb = G + b * NDIM + h;
        int4 vf = *(const int4*)(gb);
        int4 vi = *(const int4*)(gb + HDIM);
        int4 vc = *(const int4*)(gb + 2 * HDIM);
        int4 vo = *(const int4*)(gb + 3 * HDIM);
        float4 cs0 = *(const float4*)(c + e);
        float4 cs1 = *(const float4*)(c + e + 4);
        const __hip_bfloat16* pf = (const __hip_bfloat16*)&vf;
        const __hip_bfloat16* pi = (const __hip_bfloat16*)&vi;
        const __hip_bfloat16* pc = (const __hip_bfloat16*)&vc;
        const __hip_bfloat16* po = (const __hip_bfloat16*)&vo;
        float cse[8] = {cs0.x, cs0.y, cs0.z, cs0.w, cs1.x, cs1.y, cs1.z, cs1.w};
        float r[8];
        #pragma unroll
        for (int k = 0; k < 8; ++k) {
            float ft = sigmoidf_(__bfloat162float(pf[k]));
            float it = sigmoidf_(__bfloat162float(pi[k]));
            float ctt = sigmoidf_(__bfloat162float(pc[k]));
            float ot = sigmoidf_(__bfloat162float(po[k]));
            float ct = ft * cse[k] + it * ctt;
            r[k] = ot * tanhf(ct);
        }
        float4 o0 = {r[0], r[1], r[2], r[3]};
        float4 o1 = {r[4], r[5], r[6], r[7]};
        *(float4*)(out + e) = o0;
        *(float4*)(out + e + 4) = o1;
    }
}

extern "C" void kernel_launch(void* const* d_in, const int* in_sizes, int n_in,
                              void* d_out, int out_size, void* d_ws, size_t ws_size,
                              hipStream_t stream) {
    const float* x    = (const float*)d_in[0];
    const float* prev = (const float*)d_in[1];
    const float* cst  = (const float*)d_in[2];
    const float* wfg  = (const float*)d_in[3];
    const float* wig  = (const float*)d_in[4];
    const float* wog  = (const float*)d_in[5];
    const float* wol  = (const float*)d_in[6];
    float* out = (float*)d_out;

    char* ws = (char*)d_ws;
    __hip_bfloat16* Abf   = (__hip_bfloat16*)(ws);                         // 32 MB
    __hip_bfloat16* Wbf   = (__hip_bfloat16*)(ws + 33554432);              // 64 MB
    __hip_bfloat16* gates = (__hip_bfloat16*)(ws + 33554432 + 67108864);   // 64 MB

    k_concat_cast<<<2048, 256, 0, stream>>>(prev, x, Abf);
    k_cast_w<<<2048, 256, 0, stream>>>(wfg, wig, wog, wol, Wbf);
    k_gemm<<<512, 512, 0, stream>>>(Abf, Wbf, gates);
    k_cell<<<2048, 256, 0, stream>>>(gates, cst, out);
}

// Round 5
// 309.721 us; speedup vs baseline: 1.5301x; 1.0812x over previous
//
#include <hip/hip_runtime.h>
#include <hip/hip_bf16.h>
#include <cstdint>
#include <cstddef>

// ---------------------------------------------------------------------------
// LSTM cell: ht = sigmoid(o) * tanh(sigmoid(f)*c + sigmoid(i)*sigmoid(c~))
// gates = [prev_state, x] @ [W_fg;W_ig;W_og;W_ol]^T   (M=4096,N=8192,K=4096)
// GEMM: 256x256 tile, BK=64, m201 8-phase schedule. RACE-FIX vs round 4:
// counted VMW10 moved BEFORE the mid-phase barrier so every wave's stage of
// the half read next phase is certified at a common barrier (RAW chain:
// VMW10(all waves) -> BAR -> read). Prologue wait VMW12 -> VMW10 so ph1's
// A-hi(s0) read is also certified.
// ---------------------------------------------------------------------------

typedef __bf16 nbf16;
typedef nbf16 bf16x8 __attribute__((ext_vector_type(8)));
typedef float f32x4 __attribute__((ext_vector_type(4)));

static constexpr int MDIM = 4096;
static constexpr int NDIM = 8192;
static constexpr int KDIM = 4096;
static constexpr int HDIM = 2048;
static constexpr int KB   = KDIM * 2;     // K row stride in bytes

#define VMW10 asm volatile("s_waitcnt vmcnt(10)" ::: "memory")
#define VMW0  asm volatile("s_waitcnt vmcnt(0)" ::: "memory")
#define LGKM0 asm volatile("s_waitcnt lgkmcnt(0)" ::: "memory")
#define BAR   __builtin_amdgcn_s_barrier()
#define SB0   __builtin_amdgcn_sched_barrier(0)
#define PRIO1 __builtin_amdgcn_s_setprio(1)
#define PRIO0 __builtin_amdgcn_s_setprio(0)

__device__ __forceinline__ void async16(void* lds, const void* g) {
    __builtin_amdgcn_global_load_lds(
        (const __attribute__((address_space(1))) void*)g,
        (__attribute__((address_space(3))) void*)lds,
        16, 0, 0);
}

__device__ __forceinline__ float sigmoidf_(float x) {
    return 1.0f / (1.0f + __expf(-x));
}

// ---------------------------------------------------------------------------
// LDS half = 128 logical rows x 64 k (bf16) = 16 KB, 16 chunks of 1 KB (8 rows).
// Stored byte for (logical row r, 16B k-chunk c) = r*128 + (c ^ (r&7))*16.
// Stage writes linearly (gll dest = chunkbase + lane*16) with the inverse
// permutation applied to the GLOBAL source k-chunk (rule 21: both sides).
// ---------------------------------------------------------------------------
__device__ __forceinline__ void stage_A(const char* Ab, int X, int t, char* slot,
                                        int wave, int r0, int cb) {
    const char* s = Ab + (size_t)(X * 64 + r0) * KB + t * 128 + cb;
    async16(slot + wave * 1024, s);
    async16(slot + (wave + 8) * 1024, s + (size_t)128 * KB);
}
__device__ __forceinline__ void stage_B(const char* Wb, int Y, int t, char* slot,
                                        int wave, int rB0, int cb) {
    const char* s = Wb + (size_t)(rB0 + Y * 32) * KB + t * 128 + cb;
    async16(slot + wave * 1024, s);
    async16(slot + (wave + 8) * 1024, s + (size_t)128 * KB);
}

__device__ __forceinline__ void read_A(bf16x8 (&d)[4][2], const char* hb,
                                       int ar, int kc0, int kc1) {
#pragma unroll
    for (int m = 0; m < 4; ++m) {
        d[m][0] = *(const bf16x8*)(hb + ar + m * 2048 + kc0);
        d[m][1] = *(const bf16x8*)(hb + ar + m * 2048 + kc1);
    }
}
__device__ __forceinline__ void read_B(bf16x8 (&d)[2][2], const char* hb,
                                       int br, int kc0, int kc1) {
#pragma unroll
    for (int j = 0; j < 2; ++j) {
        d[j][0] = *(const bf16x8*)(hb + br + j * 2048 + kc0);
        d[j][1] = *(const bf16x8*)(hb + br + j * 2048 + kc1);
    }
}
__device__ __forceinline__ void mfma16(f32x4 (&acc)[8][4], int mh, int Y,
                                       const bf16x8 (&a)[4][2],
                                       const bf16x8 (&b)[2][2]) {
#pragma unroll
    for (int m = 0; m < 4; ++m)
#pragma unroll
        for (int j = 0; j < 2; ++j) {
            acc[mh * 4 + m][Y * 2 + j] = __builtin_amdgcn_mfma_f32_16x16x32_bf16(
                a[m][0], b[j][0], acc[mh * 4 + m][Y * 2 + j], 0, 0, 0);
            acc[mh * 4 + m][Y * 2 + j] = __builtin_amdgcn_mfma_f32_16x16x32_bf16(
                a[m][1], b[j][1], acc[mh * 4 + m][Y * 2 + j], 0, 0, 0);
        }
}

// ---- concat(prev_state, x) -> bf16 A [MDIM][KDIM] -------------------------
__global__ __launch_bounds__(256) void k_concat_cast(
        const float* __restrict__ prev, const float* __restrict__ x,
        __hip_bfloat16* __restrict__ A) {
    const size_t total8 = (size_t)MDIM * KDIM / 8;
    const size_t stride = (size_t)gridDim.x * blockDim.x;
    for (size_t i = (size_t)blockIdx.x * blockDim.x + threadIdx.x; i < total8;
         i += stride) {
        size_t e = i * 8;
        size_t b = e >> 12;
        int k = (int)(e & (KDIM - 1));
        const float* src = (k < HDIM) ? (prev + b * HDIM + k)
                                      : (x + b * HDIM + (k - HDIM));
        float4 v0 = *(const float4*)src;
        float4 v1 = *(const float4*)(src + 4);
        union { __hip_bfloat16 h[8]; int4 q; } u;
        u.h[0] = __float2bfloat16(v0.x); u.h[1] = __float2bfloat16(v0.y);
        u.h[2] = __float2bfloat16(v0.z); u.h[3] = __float2bfloat16(v0.w);
        u.h[4] = __float2bfloat16(v1.x); u.h[5] = __float2bfloat16(v1.y);
        u.h[6] = __float2bfloat16(v1.z); u.h[7] = __float2bfloat16(v1.w);
        *(int4*)(A + e) = u.q;
    }
}

// ---- [W_fg;W_ig;W_og;W_ol] -> bf16 W [NDIM][KDIM] --------------------------
__global__ __launch_bounds__(256) void k_cast_w(
        const float* __restrict__ w0, const float* __restrict__ w1,
        const float* __restrict__ w2, const float* __restrict__ w3,
        __hip_bfloat16* __restrict__ W) {
    const size_t per = (size_t)HDIM * KDIM;
    const size_t total8 = 4 * per / 8;
    const size_t stride = (size_t)gridDim.x * blockDim.x;
    for (size_t i = (size_t)blockIdx.x * blockDim.x + threadIdx.x; i < total8;
         i += stride) {
        size_t e = i * 8;
        int g = (int)(e >> 23);
        size_t rem = e & (per - 1);
        const float* src = (g == 0 ? w0 : g == 1 ? w1 : g == 2 ? w2 : w3) + rem;
        float4 v0 = *(const float4*)src;
        float4 v1 = *(const float4*)(src + 4);
        union { __hip_bfloat16 h[8]; int4 q; } u;
        u.h[0] = __float2bfloat16(v0.x); u.h[1] = __float2bfloat16(v0.y);
        u.h[2] = __float2bfloat16(v0.z); u.h[3] = __float2bfloat16(v0.w);
        u.h[4] = __float2bfloat16(v1.x); u.h[5] = __float2bfloat16(v1.y);
        u.h[6] = __float2bfloat16(v1.z); u.h[7] = __float2bfloat16(v1.w);
        *(int4*)(W + e) = u.q;
    }
}

// ---- GEMM: G[m][n] = sum_k A[m][k]*W[n][k] --------------------------------
__global__ __launch_bounds__(512, 2) void k_gemm(
        const __hip_bfloat16* __restrict__ A, const __hip_bfloat16* __restrict__ W,
        __hip_bfloat16* __restrict__ G) {
    __shared__ __align__(16) char lds[131072];

    const int bid = blockIdx.x;
    const int swz = (bid & 7) * 64 + (bid >> 3);     // T1 bijective (nwg=512)
    const int mt = swz >> 5, nt = swz & 31;
    const int brow = mt * 256, bcol = nt * 256;

    const int tid = threadIdx.x;
    const int wave = tid >> 6, lane = tid & 63;
    const int wr = wave >> 2, wc = wave & 3;         // 2x4 wave grid, 128x64 out

    const char* Ab = (const char*)A + (size_t)brow * KB;
    const char* Wb = (const char*)W + (size_t)bcol * KB;

    char* const Ah00 = lds;
    char* const Ah01 = lds + 16384;
    char* const Ah10 = lds + 32768;
    char* const Ah11 = lds + 49152;
    char* const Bh00 = lds + 65536;
    char* const Bh01 = lds + 81920;
    char* const Bh10 = lds + 98304;
    char* const Bh11 = lds + 114688;

    // stage constants
    const int r0  = wave * 8 + (lane >> 3);
    const int rB0 = ((r0 >> 5) << 6) + (r0 & 31);
    const int cb  = (((lane & 7) ^ (lane >> 3)) << 4);
    // read constants
    const int kg  = lane >> 4;
    const int ar  = (wr * 64 + (lane & 15)) * 128;
    const int br  = (wc * 32 + (lane & 15)) * 128;
    const int kc0 = ((kg ^ (lane & 7)) << 4);
    const int kc1 = (((4 + kg) ^ (lane & 7)) << 4);

    f32x4 acc[8][4] = {};
    bf16x8 a0[4][2], a1[4][2], b0[2][2], b1[2][2];

    // ---- prologue: stage tiles 0 (s0) and 1 (s1) ----
    stage_B(Wb, 0, 0, Bh00, wave, rB0, cb);
    stage_A(Ab, 0, 0, Ah00, wave, r0, cb);
    stage_A(Ab, 1, 0, Ah01, wave, r0, cb);
    stage_B(Wb, 1, 0, Bh01, wave, rB0, cb);
    stage_B(Wb, 0, 1, Bh10, wave, rB0, cb);
    stage_A(Ab, 0, 1, Ah10, wave, r0, cb);
    stage_A(Ab, 1, 1, Ah11, wave, r0, cb);
    stage_B(Wb, 1, 1, Bh11, wave, rB0, cb);
    VMW10;                    // certify B-lo(s0), A-lo(s0), A-hi(s0) (loads 1-6)
    SB0; BAR;
    read_A(a0, Ah00, ar, kc0, kc1);    // A-lo(s0) -> a0
    read_B(b0, Bh00, br, kc0, kc1);    // B-lo(s0) -> b0

    // ---- main loop: 32 iterations x 2 K-tiles ----
    // Phase p: reads(certified at p-1's mid-BAR); stage; VMW10 (certifies
    // stage(p-5), read at p+1); BAR; LGKM0; MFMA; BAR.
    for (int i = 0; i < 32; ++i) {
        const int t2 = (2 * i + 2) & 63;
        const int t3 = (2 * i + 3) & 63;

        // ph1: mfma (mh0,Y0) tau0 [a0,b0]; read A-hi(s0)->a1; stage B-lo(s0,t2)
        read_A(a1, Ah01, ar, kc0, kc1);
        stage_B(Wb, 0, t2, Bh00, wave, rB0, cb);
        VMW10; SB0; BAR; LGKM0; SB0;
        PRIO1; mfma16(acc, 0, 0, a0, b0); PRIO0;
        SB0; BAR;
        // ph2: mfma (mh1,Y0) tau0 [a1,b0]; read B-hi(s0)->b1; stage A-lo(s0,t2)
        read_B(b1, Bh01, br, kc0, kc1);
        stage_A(Ab, 0, t2, Ah00, wave, r0, cb);
        VMW10; SB0; BAR; LGKM0; SB0;
        PRIO1; mfma16(acc, 1, 0, a1, b0); PRIO0;
        SB0; BAR;
        // ph3: mfma (mh1,Y1) tau0 [a1,b1]; read B-lo(s1)->b0; stage A-hi(s0,t2)
        read_B(b0, Bh10, br, kc0, kc1);
        stage_A(Ab, 1, t2, Ah01, wave, r0, cb);
        VMW10; SB0; BAR; LGKM0; SB0;
        PRIO1; mfma16(acc, 1, 1, a1, b1); PRIO0;
        SB0; BAR;
        // ph4: mfma (mh0,Y1) tau0 [a0,b1]; read A-lo(s1)->a1; stage B-hi(s0,t2)
        read_A(a1, Ah10, ar, kc0, kc1);
        stage_B(Wb, 1, t2, Bh01, wave, rB0, cb);
        VMW10; SB0; BAR; LGKM0; SB0;
        PRIO1; mfma16(acc, 0, 1, a0, b1); PRIO0;
        SB0; BAR;
        // ph5: mfma (mh0,Y0) tau1 [a1,b0]; read A-hi(s1)->a0; stage B-lo(s1,t3)
        read_A(a0, Ah11, ar, kc0, kc1);
        stage_B(Wb, 0, t3, Bh10, wave, rB0, cb);
        VMW10; SB0; BAR; LGKM0; SB0;
        PRIO1; mfma16(acc, 0, 0, a1, b0); PRIO0;
        SB0; BAR;
        // ph6: mfma (mh1,Y0) tau1 [a0,b0]; read B-hi(s1)->b1; stage A-lo(s1,t3)
        read_B(b1, Bh11, br, kc0, kc1);
        stage_A(Ab, 0, t3, Ah10, wave, r0, cb);
        VMW10; SB0; BAR; LGKM0; SB0;
        PRIO1; mfma16(acc, 1, 0, a0, b0); PRIO0;
        SB0; BAR;
        // ph7: mfma (mh1,Y1) tau1 [a0,b1]; read B-lo(s0,t2)->b0; stage A-hi(s1,t3)
        read_B(b0, Bh00, br, kc0, kc1);
        stage_A(Ab, 1, t3, Ah11, wave, r0, cb);
        VMW10; SB0; BAR; LGKM0; SB0;
        PRIO1; mfma16(acc, 1, 1, a0, b1); PRIO0;
        SB0; BAR;
        // ph8: mfma (mh0,Y1) tau1 [a1,b1]; read A-lo(s0,t2)->a0; stage B-hi(s1,t3)
        read_A(a0, Ah00, ar, kc0, kc1);
        stage_B(Wb, 1, t3, Bh11, wave, rB0, cb);
        VMW10; SB0; BAR; LGKM0; SB0;
        PRIO1; mfma16(acc, 0, 1, a1, b1); PRIO0;
        SB0; BAR;
    }

    // ---- epilogue: drain stages, repack C tile through LDS, int4 stores ----
    VMW0;
    BAR;
    __hip_bfloat16* cl = (__hip_bfloat16*)lds;   // [256][256] bf16 = 128 KB
    {
        const int rb = wr * 128 + ((lane >> 4) << 2);
        const int cbase = wc * 64 + (lane & 15);
        #pragma unroll
        for (int mi = 0; mi < 8; ++mi)
            #pragma unroll
            for (int ni = 0; ni < 4; ++ni)
                #pragma unroll
                for (int q = 0; q < 4; ++q)
                    cl[(rb + mi * 16 + q) * 256 + (cbase + ni * 16)] =
                        __float2bfloat16(acc[mi][ni][q]);
    }
    BAR;
    #pragma unroll
    for (int j = 0; j < 16; ++j) {
        const int o = j * 8192 + tid * 16;
        const int r = o >> 9, cbyte = o & 511;
        *(int4*)((char*)G + ((size_t)(brow + r) * NDIM + bcol) * 2 + cbyte) =
            *(const int4*)(lds + o);
    }
}

// ---- cell update: ht = sig(o)*tanh(sig(f)*c + sig(i)*sig(c~)) --------------
__global__ __launch_bounds__(256) void k_cell(
        const __hip_bfloat16* __restrict__ G, const float* __restrict__ c,
        float* __restrict__ out) {
    const size_t total8 = (size_t)MDIM * HDIM / 8;
    const size_t stride = (size_t)gridDim.x * blockDim.x;
    for (size_t i = (size_t)blockIdx.x * blockDim.x + threadIdx.x; i < total8;
         i += stride) {
        size_t e = i * 8;
        size_t b = e >> 11;
        int h = (int)(e & (HDIM - 1));
        const __hip_bfloat16* gb = G + b * NDIM + h;
        int4 vf = *(const int4*)(gb);
        int4 vi = *(const int4*)(gb + HDIM);
        int4 vc = *(const int4*)(gb + 2 * HDIM);
        int4 vo = *(const int4*)(gb + 3 * HDIM);
        float4 cs0 = *(const float4*)(c + e);
        float4 cs1 = *(const float4*)(c + e + 4);
        const __hip_bfloat16* pf = (const __hip_bfloat16*)&vf;
        const __hip_bfloat16* pi = (const __hip_bfloat16*)&vi;
        const __hip_bfloat16* pc = (const __hip_bfloat16*)&vc;
        const __hip_bfloat16* po = (const __hip_bfloat16*)&vo;
        float cse[8] = {cs0.x, cs0.y, cs0.z, cs0.w, cs1.x, cs1.y, cs1.z, cs1.w};
        float r[8];
        #pragma unroll
        for (int k = 0; k < 8; ++k) {
            float ft = sigmoidf_(__bfloat162float(pf[k]));
            float it = sigmoidf_(__bfloat162float(pi[k]));
            float ctt = sigmoidf_(__bfloat162float(pc[k]));
            float ot = sigmoidf_(__bfloat162float(po[k]));
            float ct = ft * cse[k] + it * ctt;
            r[k] = ot * tanhf(ct);
        }
        float4 o0 = {r[0], r[1], r[2], r[3]};
        float4 o1 = {r[4], r[5], r[6], r[7]};
        *(float4*)(out + e) = o0;
        *(float4*)(out + e + 4) = o1;
    }
}

extern "C" void kernel_launch(void* const* d_in, const int* in_sizes, int n_in,
                              void* d_out, int out_size, void* d_ws, size_t ws_size,
                              hipStream_t stream) {
    const float* x    = (const float*)d_in[0];
    const float* prev = (const float*)d_in[1];
    const float* cst  = (const float*)d_in[2];
    const float* wfg  = (const float*)d_in[3];
    const float* wig  = (const float*)d_in[4];
    const float* wog  = (const float*)d_in[5];
    const float* wol  = (const float*)d_in[6];
    float* out = (float*)d_out;

    char* ws = (char*)d_ws;
    __hip_bfloat16* Abf   = (__hip_bfloat16*)(ws);                         // 32 MB
    __hip_bfloat16* Wbf   = (__hip_bfloat16*)(ws + 33554432);              // 64 MB
    __hip_bfloat16* gates = (__hip_bfloat16*)(ws + 33554432 + 67108864);   // 64 MB

    k_concat_cast<<<2048, 256, 0, stream>>>(prev, x, Abf);
    k_cast_w<<<2048, 256, 0, stream>>>(wfg, wig, wog, wol, Wbf);
    k_gemm<<<512, 512, 0, stream>>>(Abf, Wbf, gates);
    k_cell<<<2048, 256, 0, stream>>>(gates, cst, out);
}

// Round 6
// 286.990 us; speedup vs baseline: 1.6513x; 1.0792x over previous
//
#include <hip/hip_runtime.h>
#include <hip/hip_bf16.h>
#include <cstdint>
#include <cstddef>

// ---------------------------------------------------------------------------
// LSTM cell: ht = sigmoid(o) * tanh(sigmoid(f)*c + sigmoid(i)*sigmoid(c~))
// gates = [prev_state, x] @ W'^T with W' row-interleaved: W'[4h+g] = W_g[h].
// One 256-col GEMM tile holds all 4 gates for 64 h -> cell update fused into
// the GEMM epilogue; gate pre-activations never touch HBM.
// GEMM core: 256x256, BK=64, m201 8-phase counted-vmcnt schedule (unchanged
// from round 5 — proven race-free). New: 2-D XCD swizzle (8x8 sub-grid per
// XCD) to cut cross-XCD B-panel re-fetch.
// ---------------------------------------------------------------------------

typedef __bf16 nbf16;
typedef nbf16 bf16x8 __attribute__((ext_vector_type(8)));
typedef float f32x4 __attribute__((ext_vector_type(4)));

static constexpr int MDIM = 4096;
static constexpr int NDIM = 8192;
static constexpr int KDIM = 4096;
static constexpr int HDIM = 2048;
static constexpr int KB   = KDIM * 2;     // K row stride in bytes

#define VMW10 asm volatile("s_waitcnt vmcnt(10)" ::: "memory")
#define VMW0  asm volatile("s_waitcnt vmcnt(0)" ::: "memory")
#define LGKM0 asm volatile("s_waitcnt lgkmcnt(0)" ::: "memory")
#define BAR   __builtin_amdgcn_s_barrier()
#define SB0   __builtin_amdgcn_sched_barrier(0)
#define PRIO1 __builtin_amdgcn_s_setprio(1)
#define PRIO0 __builtin_amdgcn_s_setprio(0)

__device__ __forceinline__ void async16(void* lds, const void* g) {
    __builtin_amdgcn_global_load_lds(
        (const __attribute__((address_space(1))) void*)g,
        (__attribute__((address_space(3))) void*)lds,
        16, 0, 0);
}

__device__ __forceinline__ float sigmoidf_(float x) {
    return 1.0f / (1.0f + __expf(-x));
}

// LDS half = 128 rows x 64 k bf16 = 16 KB; stored chunk = logical ^ (row&7),
// realized as linear LDS dest + inverse-permuted global source (rule 21).
__device__ __forceinline__ void stage_A(const char* Ab, int X, int t, char* slot,
                                        int wave, int r0, int cb) {
    const char* s = Ab + (size_t)(X * 64 + r0) * KB + t * 128 + cb;
    async16(slot + wave * 1024, s);
    async16(slot + (wave + 8) * 1024, s + (size_t)128 * KB);
}
__device__ __forceinline__ void stage_B(const char* Wb, int Y, int t, char* slot,
                                        int wave, int rB0, int cb) {
    const char* s = Wb + (size_t)(rB0 + Y * 32) * KB + t * 128 + cb;
    async16(slot + wave * 1024, s);
    async16(slot + (wave + 8) * 1024, s + (size_t)128 * KB);
}

__device__ __forceinline__ void read_A(bf16x8 (&d)[4][2], const char* hb,
                                       int ar, int kc0, int kc1) {
#pragma unroll
    for (int m = 0; m < 4; ++m) {
        d[m][0] = *(const bf16x8*)(hb + ar + m * 2048 + kc0);
        d[m][1] = *(const bf16x8*)(hb + ar + m * 2048 + kc1);
    }
}
__device__ __forceinline__ void read_B(bf16x8 (&d)[2][2], const char* hb,
                                       int br, int kc0, int kc1) {
#pragma unroll
    for (int j = 0; j < 2; ++j) {
        d[j][0] = *(const bf16x8*)(hb + br + j * 2048 + kc0);
        d[j][1] = *(const bf16x8*)(hb + br + j * 2048 + kc1);
    }
}
__device__ __forceinline__ void mfma16(f32x4 (&acc)[8][4], int mh, int Y,
                                       const bf16x8 (&a)[4][2],
                                       const bf16x8 (&b)[2][2]) {
#pragma unroll
    for (int m = 0; m < 4; ++m)
#pragma unroll
        for (int j = 0; j < 2; ++j) {
            acc[mh * 4 + m][Y * 2 + j] = __builtin_amdgcn_mfma_f32_16x16x32_bf16(
                a[m][0], b[j][0], acc[mh * 4 + m][Y * 2 + j], 0, 0, 0);
            acc[mh * 4 + m][Y * 2 + j] = __builtin_amdgcn_mfma_f32_16x16x32_bf16(
                a[m][1], b[j][1], acc[mh * 4 + m][Y * 2 + j], 0, 0, 0);
        }
}

// ---- concat(prev_state, x) -> bf16 A [MDIM][KDIM] -------------------------
__global__ __launch_bounds__(256) void k_concat_cast(
        const float* __restrict__ prev, const float* __restrict__ x,
        __hip_bfloat16* __restrict__ A) {
    const size_t total8 = (size_t)MDIM * KDIM / 8;
    const size_t stride = (size_t)gridDim.x * blockDim.x;
    for (size_t i = (size_t)blockIdx.x * blockDim.x + threadIdx.x; i < total8;
         i += stride) {
        size_t e = i * 8;
        size_t b = e >> 12;
        int k = (int)(e & (KDIM - 1));
        const float* src = (k < HDIM) ? (prev + b * HDIM + k)
                                      : (x + b * HDIM + (k - HDIM));
        float4 v0 = *(const float4*)src;
        float4 v1 = *(const float4*)(src + 4);
        union { __hip_bfloat16 h[8]; int4 q; } u;
        u.h[0] = __float2bfloat16(v0.x); u.h[1] = __float2bfloat16(v0.y);
        u.h[2] = __float2bfloat16(v0.z); u.h[3] = __float2bfloat16(v0.w);
        u.h[4] = __float2bfloat16(v1.x); u.h[5] = __float2bfloat16(v1.y);
        u.h[6] = __float2bfloat16(v1.z); u.h[7] = __float2bfloat16(v1.w);
        *(int4*)(A + e) = u.q;
    }
}

// ---- gate-interleaved W': row n = W_{n&3}[n>>2], bf16 [NDIM][KDIM] ---------
__global__ __launch_bounds__(256) void k_cast_w(
        const float* __restrict__ w0, const float* __restrict__ w1,
        const float* __restrict__ w2, const float* __restrict__ w3,
        __hip_bfloat16* __restrict__ W) {
    const size_t total8 = (size_t)NDIM * KDIM / 8;
    const size_t stride = (size_t)gridDim.x * blockDim.x;
    for (size_t i = (size_t)blockIdx.x * blockDim.x + threadIdx.x; i < total8;
         i += stride) {
        size_t e = i * 8;
        int n = (int)(e >> 12);
        int k = (int)(e & (KDIM - 1));
        int g = n & 3;
        size_t h = (size_t)(n >> 2);
        const float* src = (g == 0 ? w0 : g == 1 ? w1 : g == 2 ? w2 : w3)
                           + h * KDIM + k;
        float4 v0 = *(const float4*)src;
        float4 v1 = *(const float4*)(src + 4);
        union { __hip_bfloat16 h[8]; int4 q; } u;
        u.h[0] = __float2bfloat16(v0.x); u.h[1] = __float2bfloat16(v0.y);
        u.h[2] = __float2bfloat16(v0.z); u.h[3] = __float2bfloat16(v0.w);
        u.h[4] = __float2bfloat16(v1.x); u.h[5] = __float2bfloat16(v1.y);
        u.h[6] = __float2bfloat16(v1.z); u.h[7] = __float2bfloat16(v1.w);
        *(int4*)(W + e) = u.q;
    }
}

// ---- GEMM + fused LSTM cell epilogue ---------------------------------------
__global__ __launch_bounds__(512, 2) void k_gemm(
        const __hip_bfloat16* __restrict__ A, const __hip_bfloat16* __restrict__ W,
        const float* __restrict__ c, float* __restrict__ out) {
    __shared__ __align__(16) char lds[131072];

    // 2-D XCD swizzle: XCD (bid&7) owns an 8(mt) x 8(nt) sub-grid (bijective)
    const int bid = blockIdx.x;
    const int xcd = bid & 7, j = bid >> 3;          // j in [0,64)
    const int mt = (xcd >> 2) * 8 + (j >> 3);       // [0,16)
    const int nt = (xcd & 3) * 8 + (j & 7);         // [0,32)
    const int brow = mt * 256, bcol = nt * 256;

    const int tid = threadIdx.x;
    const int wave = tid >> 6, lane = tid & 63;
    const int wr = wave >> 2, wc = wave & 3;        // 2x4 wave grid, 128x64 out

    const char* Ab = (const char*)A + (size_t)brow * KB;
    const char* Wb = (const char*)W + (size_t)bcol * KB;

    char* const Ah00 = lds;
    char* const Ah01 = lds + 16384;
    char* const Ah10 = lds + 32768;
    char* const Ah11 = lds + 49152;
    char* const Bh00 = lds + 65536;
    char* const Bh01 = lds + 81920;
    char* const Bh10 = lds + 98304;
    char* const Bh11 = lds + 114688;

    const int r0  = wave * 8 + (lane >> 3);
    const int rB0 = ((r0 >> 5) << 6) + (r0 & 31);
    const int cb  = (((lane & 7) ^ (lane >> 3)) << 4);
    const int kg  = lane >> 4;
    const int ar  = (wr * 64 + (lane & 15)) * 128;
    const int br  = (wc * 32 + (lane & 15)) * 128;
    const int kc0 = ((kg ^ (lane & 7)) << 4);
    const int kc1 = (((4 + kg) ^ (lane & 7)) << 4);

    f32x4 acc[8][4] = {};
    bf16x8 a0[4][2], a1[4][2], b0[2][2], b1[2][2];

    // ---- prologue: stage tiles 0 (s0) and 1 (s1) ----
    stage_B(Wb, 0, 0, Bh00, wave, rB0, cb);
    stage_A(Ab, 0, 0, Ah00, wave, r0, cb);
    stage_A(Ab, 1, 0, Ah01, wave, r0, cb);
    stage_B(Wb, 1, 0, Bh01, wave, rB0, cb);
    stage_B(Wb, 0, 1, Bh10, wave, rB0, cb);
    stage_A(Ab, 0, 1, Ah10, wave, r0, cb);
    stage_A(Ab, 1, 1, Ah11, wave, r0, cb);
    stage_B(Wb, 1, 1, Bh11, wave, rB0, cb);
    VMW10;
    SB0; BAR;
    read_A(a0, Ah00, ar, kc0, kc1);
    read_B(b0, Bh00, br, kc0, kc1);

    // ---- main loop: 32 iterations x 2 K-tiles (unchanged from round 5) ----
    for (int i = 0; i < 32; ++i) {
        const int t2 = (2 * i + 2) & 63;
        const int t3 = (2 * i + 3) & 63;

        read_A(a1, Ah01, ar, kc0, kc1);
        stage_B(Wb, 0, t2, Bh00, wave, rB0, cb);
        VMW10; SB0; BAR; LGKM0; SB0;
        PRIO1; mfma16(acc, 0, 0, a0, b0); PRIO0;
        SB0; BAR;

        read_B(b1, Bh01, br, kc0, kc1);
        stage_A(Ab, 0, t2, Ah00, wave, r0, cb);
        VMW10; SB0; BAR; LGKM0; SB0;
        PRIO1; mfma16(acc, 1, 0, a1, b0); PRIO0;
        SB0; BAR;

        read_B(b0, Bh10, br, kc0, kc1);
        stage_A(Ab, 1, t2, Ah01, wave, r0, cb);
        VMW10; SB0; BAR; LGKM0; SB0;
        PRIO1; mfma16(acc, 1, 1, a1, b1); PRIO0;
        SB0; BAR;

        read_A(a1, Ah10, ar, kc0, kc1);
        stage_B(Wb, 1, t2, Bh01, wave, rB0, cb);
        VMW10; SB0; BAR; LGKM0; SB0;
        PRIO1; mfma16(acc, 0, 1, a0, b1); PRIO0;
        SB0; BAR;

        read_A(a0, Ah11, ar, kc0, kc1);
        stage_B(Wb, 0, t3, Bh10, wave, rB0, cb);
        VMW10; SB0; BAR; LGKM0; SB0;
        PRIO1; mfma16(acc, 0, 0, a1, b0); PRIO0;
        SB0; BAR;

        read_B(b1, Bh11, br, kc0, kc1);
        stage_A(Ab, 0, t3, Ah10, wave, r0, cb);
        VMW10; SB0; BAR; LGKM0; SB0;
        PRIO1; mfma16(acc, 1, 0, a0, b0); PRIO0;
        SB0; BAR;

        read_B(b0, Bh00, br, kc0, kc1);
        stage_A(Ab, 1, t3, Ah11, wave, r0, cb);
        VMW10; SB0; BAR; LGKM0; SB0;
        PRIO1; mfma16(acc, 1, 1, a0, b1); PRIO0;
        SB0; BAR;

        read_A(a0, Ah00, ar, kc0, kc1);
        stage_B(Wb, 1, t3, Bh11, wave, rB0, cb);
        VMW10; SB0; BAR; LGKM0; SB0;
        PRIO1; mfma16(acc, 0, 1, a1, b1); PRIO0;
        SB0; BAR;
    }

    // ---- fused cell epilogue: two 128-row passes through LDS ----
    // cols n = bcol + c: gate g = c&3 of h = (bcol+c)>>2 -> 16 cols = 4 h's.
    VMW0;
    BAR;
    __hip_bfloat16* cl = (__hip_bfloat16*)lds;      // [128][256] bf16 = 64 KB
    const int h0 = bcol >> 2;
    #pragma unroll
    for (int p = 0; p < 2; ++p) {
        if (p) BAR;                     // pass-0 reads done before overwrite
        if (wr == p) {
            const int rb = ((lane >> 4) << 2);
            const int cbase = wc * 64 + (lane & 15);
            #pragma unroll
            for (int mi = 0; mi < 8; ++mi)
                #pragma unroll
                for (int ni = 0; ni < 4; ++ni)
                    #pragma unroll
                    for (int q = 0; q < 4; ++q)
                        cl[(rb + mi * 16 + q) * 256 + (cbase + ni * 16)] =
                            __float2bfloat16(acc[mi][ni][q]);
        }
        BAR;
        #pragma unroll
        for (int rnd = 0; rnd < 4; ++rnd) {
            const int row = rnd * 32 + (tid >> 4);
            const int ccol = (tid & 15) * 16;
            union { int4 q[2]; __hip_bfloat16 h[16]; } v;
            v.q[0] = *(const int4*)&cl[row * 256 + ccol];
            v.q[1] = *(const int4*)&cl[row * 256 + ccol + 8];
            const size_t R = (size_t)(brow + p * 128 + row);
            const int hh = h0 + (tid & 15) * 4;
            float4 cc = *(const float4*)(c + R * HDIM + hh);
            float cs[4] = {cc.x, cc.y, cc.z, cc.w};
            float ht[4];
            #pragma unroll
            for (int u = 0; u < 4; ++u) {
                float ft  = sigmoidf_(__bfloat162float(v.h[4 * u + 0]));
                float it  = sigmoidf_(__bfloat162float(v.h[4 * u + 1]));
                float ctt = sigmoidf_(__bfloat162float(v.h[4 * u + 2]));
                float ot  = sigmoidf_(__bfloat162float(v.h[4 * u + 3]));
                float ct  = ft * cs[u] + it * ctt;
                ht[u] = ot * tanhf(ct);
            }
            float4 o = {ht[0], ht[1], ht[2], ht[3]};
            *(float4*)(out + R * HDIM + hh) = o;
        }
    }
}

extern "C" void kernel_launch(void* const* d_in, const int* in_sizes, int n_in,
                              void* d_out, int out_size, void* d_ws, size_t ws_size,
                              hipStream_t stream) {
    const float* x    = (const float*)d_in[0];
    const float* prev = (const float*)d_in[1];
    const float* cst  = (const float*)d_in[2];
    const float* wfg  = (const float*)d_in[3];
    const float* wig  = (const float*)d_in[4];
    const float* wog  = (const float*)d_in[5];
    const float* wol  = (const float*)d_in[6];
    float* out = (float*)d_out;

    char* ws = (char*)d_ws;
    __hip_bfloat16* Abf = (__hip_bfloat16*)(ws);                 // 32 MB
    __hip_bfloat16* Wbf = (__hip_bfloat16*)(ws + 33554432);      // 64 MB

    k_concat_cast<<<2048, 256, 0, stream>>>(prev, x, Abf);
    k_cast_w<<<2048, 256, 0, stream>>>(wfg, wig, wog, wol, Wbf);
    k_gemm<<<512, 512, 0, stream>>>(Abf, Wbf, cst, out);
}

// Round 7
// 272.933 us; speedup vs baseline: 1.7364x; 1.0515x over previous
//
#include <hip/hip_runtime.h>
#include <hip/hip_bf16.h>
#include <cstdint>
#include <cstddef>

// ---------------------------------------------------------------------------
// LSTM cell: ht = sigmoid(o) * tanh(sigmoid(f)*c + sigmoid(i)*sigmoid(c~))
// gates = [prev_state, x] @ W'^T with W' row-interleaved: W'[4h+g] = W_g[h].
// Cell update fused into GEMM epilogue (gates never touch HBM).
// GEMM core: 256x256, BK=64, 8-phase counted-vmcnt schedule. This round:
// counted lgkmcnt(R_p) instead of lgkmcnt(0) -> this phase's ds_reads overlap
// this phase's MFMA (reads are consumed one phase later); fast sigmoid/tanh
// (v_exp + v_rcp) in the epilogue.
// ---------------------------------------------------------------------------

typedef __bf16 nbf16;
typedef nbf16 bf16x8 __attribute__((ext_vector_type(8)));
typedef float f32x4 __attribute__((ext_vector_type(4)));

static constexpr int MDIM = 4096;
static constexpr int NDIM = 8192;
static constexpr int KDIM = 4096;
static constexpr int HDIM = 2048;
static constexpr int KB   = KDIM * 2;     // K row stride in bytes

#define VMW10 asm volatile("s_waitcnt vmcnt(10)" ::: "memory")
#define VMW0  asm volatile("s_waitcnt vmcnt(0)" ::: "memory")
#define LGKM0 asm volatile("s_waitcnt lgkmcnt(0)" ::: "memory")
// counted: wait until only THIS phase's n ds_reads are outstanding
#define LGKM4 asm volatile("s_waitcnt lgkmcnt(4)" ::: "memory")
#define LGKM8 asm volatile("s_waitcnt lgkmcnt(8)" ::: "memory")
#define BAR   __builtin_amdgcn_s_barrier()
#define SB0   __builtin_amdgcn_sched_barrier(0)
#define PRIO1 __builtin_amdgcn_s_setprio(1)
#define PRIO0 __builtin_amdgcn_s_setprio(0)

__device__ __forceinline__ void async16(void* lds, const void* g) {
    __builtin_amdgcn_global_load_lds(
        (const __attribute__((address_space(1))) void*)g,
        (__attribute__((address_space(3))) void*)lds,
        16, 0, 0);
}

__device__ __forceinline__ float fsig(float x) {
    return __builtin_amdgcn_rcpf(1.0f + __expf(-x));
}
__device__ __forceinline__ float ftanh(float x) {
    return 2.0f * __builtin_amdgcn_rcpf(1.0f + __expf(-2.0f * x)) - 1.0f;
}

// LDS half = 128 rows x 64 k bf16 = 16 KB; stored chunk = logical ^ (row&7),
// realized as linear LDS dest + inverse-permuted global source (rule 21).
__device__ __forceinline__ void stage_A(const char* Ab, int X, int t, char* slot,
                                        int wave, int r0, int cb) {
    const char* s = Ab + (size_t)(X * 64 + r0) * KB + t * 128 + cb;
    async16(slot + wave * 1024, s);
    async16(slot + (wave + 8) * 1024, s + (size_t)128 * KB);
}
__device__ __forceinline__ void stage_B(const char* Wb, int Y, int t, char* slot,
                                        int wave, int rB0, int cb) {
    const char* s = Wb + (size_t)(rB0 + Y * 32) * KB + t * 128 + cb;
    async16(slot + wave * 1024, s);
    async16(slot + (wave + 8) * 1024, s + (size_t)128 * KB);
}

__device__ __forceinline__ void read_A(bf16x8 (&d)[4][2], const char* hb,
                                       int ar, int kc0, int kc1) {
#pragma unroll
    for (int m = 0; m < 4; ++m) {
        d[m][0] = *(const bf16x8*)(hb + ar + m * 2048 + kc0);
        d[m][1] = *(const bf16x8*)(hb + ar + m * 2048 + kc1);
    }
}
__device__ __forceinline__ void read_B(bf16x8 (&d)[2][2], const char* hb,
                                       int br, int kc0, int kc1) {
#pragma unroll
    for (int j = 0; j < 2; ++j) {
        d[j][0] = *(const bf16x8*)(hb + br + j * 2048 + kc0);
        d[j][1] = *(const bf16x8*)(hb + br + j * 2048 + kc1);
    }
}
__device__ __forceinline__ void mfma16(f32x4 (&acc)[8][4], int mh, int Y,
                                       const bf16x8 (&a)[4][2],
                                       const bf16x8 (&b)[2][2]) {
#pragma unroll
    for (int m = 0; m < 4; ++m)
#pragma unroll
        for (int j = 0; j < 2; ++j) {
            acc[mh * 4 + m][Y * 2 + j] = __builtin_amdgcn_mfma_f32_16x16x32_bf16(
                a[m][0], b[j][0], acc[mh * 4 + m][Y * 2 + j], 0, 0, 0);
            acc[mh * 4 + m][Y * 2 + j] = __builtin_amdgcn_mfma_f32_16x16x32_bf16(
                a[m][1], b[j][1], acc[mh * 4 + m][Y * 2 + j], 0, 0, 0);
        }
}

// ---- concat(prev_state, x) -> bf16 A [MDIM][KDIM] -------------------------
__global__ __launch_bounds__(256) void k_concat_cast(
        const float* __restrict__ prev, const float* __restrict__ x,
        __hip_bfloat16* __restrict__ A) {
    const size_t total8 = (size_t)MDIM * KDIM / 8;
    const size_t stride = (size_t)gridDim.x * blockDim.x;
    for (size_t i = (size_t)blockIdx.x * blockDim.x + threadIdx.x; i < total8;
         i += stride) {
        size_t e = i * 8;
        size_t b = e >> 12;
        int k = (int)(e & (KDIM - 1));
        const float* src = (k < HDIM) ? (prev + b * HDIM + k)
                                      : (x + b * HDIM + (k - HDIM));
        float4 v0 = *(const float4*)src;
        float4 v1 = *(const float4*)(src + 4);
        union { __hip_bfloat16 h[8]; int4 q; } u;
        u.h[0] = __float2bfloat16(v0.x); u.h[1] = __float2bfloat16(v0.y);
        u.h[2] = __float2bfloat16(v0.z); u.h[3] = __float2bfloat16(v0.w);
        u.h[4] = __float2bfloat16(v1.x); u.h[5] = __float2bfloat16(v1.y);
        u.h[6] = __float2bfloat16(v1.z); u.h[7] = __float2bfloat16(v1.w);
        *(int4*)(A + e) = u.q;
    }
}

// ---- gate-interleaved W': row n = W_{n&3}[n>>2], bf16 [NDIM][KDIM] ---------
__global__ __launch_bounds__(256) void k_cast_w(
        const float* __restrict__ w0, const float* __restrict__ w1,
        const float* __restrict__ w2, const float* __restrict__ w3,
        __hip_bfloat16* __restrict__ W) {
    const size_t total8 = (size_t)NDIM * KDIM / 8;
    const size_t stride = (size_t)gridDim.x * blockDim.x;
    for (size_t i = (size_t)blockIdx.x * blockDim.x + threadIdx.x; i < total8;
         i += stride) {
        size_t e = i * 8;
        int n = (int)(e >> 12);
        int k = (int)(e & (KDIM - 1));
        int g = n & 3;
        size_t h = (size_t)(n >> 2);
        const float* src = (g == 0 ? w0 : g == 1 ? w1 : g == 2 ? w2 : w3)
                           + h * KDIM + k;
        float4 v0 = *(const float4*)src;
        float4 v1 = *(const float4*)(src + 4);
        union { __hip_bfloat16 h[8]; int4 q; } u;
        u.h[0] = __float2bfloat16(v0.x); u.h[1] = __float2bfloat16(v0.y);
        u.h[2] = __float2bfloat16(v0.z); u.h[3] = __float2bfloat16(v0.w);
        u.h[4] = __float2bfloat16(v1.x); u.h[5] = __float2bfloat16(v1.y);
        u.h[6] = __float2bfloat16(v1.z); u.h[7] = __float2bfloat16(v1.w);
        *(int4*)(W + e) = u.q;
    }
}

// ---- GEMM + fused LSTM cell epilogue ---------------------------------------
__global__ __launch_bounds__(512, 2) void k_gemm(
        const __hip_bfloat16* __restrict__ A, const __hip_bfloat16* __restrict__ W,
        const float* __restrict__ c, float* __restrict__ out) {
    __shared__ __align__(16) char lds[131072];

    // 2-D XCD swizzle: XCD (bid&7) owns an 8(mt) x 8(nt) sub-grid (bijective)
    const int bid = blockIdx.x;
    const int xcd = bid & 7, j = bid >> 3;
    const int mt = (xcd >> 2) * 8 + (j >> 3);
    const int nt = (xcd & 3) * 8 + (j & 7);
    const int brow = mt * 256, bcol = nt * 256;

    const int tid = threadIdx.x;
    const int wave = tid >> 6, lane = tid & 63;
    const int wr = wave >> 2, wc = wave & 3;

    const char* Ab = (const char*)A + (size_t)brow * KB;
    const char* Wb = (const char*)W + (size_t)bcol * KB;

    char* const Ah00 = lds;
    char* const Ah01 = lds + 16384;
    char* const Ah10 = lds + 32768;
    char* const Ah11 = lds + 49152;
    char* const Bh00 = lds + 65536;
    char* const Bh01 = lds + 81920;
    char* const Bh10 = lds + 98304;
    char* const Bh11 = lds + 114688;

    const int r0  = wave * 8 + (lane >> 3);
    const int rB0 = ((r0 >> 5) << 6) + (r0 & 31);
    const int cb  = (((lane & 7) ^ (lane >> 3)) << 4);
    const int kg  = lane >> 4;
    const int ar  = (wr * 64 + (lane & 15)) * 128;
    const int br  = (wc * 32 + (lane & 15)) * 128;
    const int kc0 = ((kg ^ (lane & 7)) << 4);
    const int kc1 = (((4 + kg) ^ (lane & 7)) << 4);

    f32x4 acc[8][4] = {};
    bf16x8 a0[4][2], a1[4][2], b0[2][2], b1[2][2];

    // ---- prologue: stage tiles 0 (s0) and 1 (s1) ----
    stage_B(Wb, 0, 0, Bh00, wave, rB0, cb);
    stage_A(Ab, 0, 0, Ah00, wave, r0, cb);
    stage_A(Ab, 1, 0, Ah01, wave, r0, cb);
    stage_B(Wb, 1, 0, Bh01, wave, rB0, cb);
    stage_B(Wb, 0, 1, Bh10, wave, rB0, cb);
    stage_A(Ab, 0, 1, Ah10, wave, r0, cb);
    stage_A(Ab, 1, 1, Ah11, wave, r0, cb);
    stage_B(Wb, 1, 1, Bh11, wave, rB0, cb);
    VMW10;
    SB0; BAR;
    read_A(a0, Ah00, ar, kc0, kc1);
    read_B(b0, Bh00, br, kc0, kc1);

    // ---- main loop: 32 iterations x 2 K-tiles ----
    // Phase p: reads(p) for MFMA at p+1; stage; VMW10; BAR; lgkmcnt(R_p)
    // (certifies reads of p-1, leaves this phase's R_p in flight -> LDS pipe
    // overlaps the MFMA cluster); MFMA(uses p-1 reads); BAR.
    for (int i = 0; i < 32; ++i) {
        const int t2 = (2 * i + 2) & 63;
        const int t3 = (2 * i + 3) & 63;

        read_A(a1, Ah01, ar, kc0, kc1);                 // 8 lgkm
        stage_B(Wb, 0, t2, Bh00, wave, rB0, cb);
        VMW10; SB0; BAR; LGKM8; SB0;
        PRIO1; mfma16(acc, 0, 0, a0, b0); PRIO0;
        SB0; BAR;

        read_B(b1, Bh01, br, kc0, kc1);                 // 4 lgkm
        stage_A(Ab, 0, t2, Ah00, wave, r0, cb);
        VMW10; SB0; BAR; LGKM4; SB0;
        PRIO1; mfma16(acc, 1, 0, a1, b0); PRIO0;
        SB0; BAR;

        read_B(b0, Bh10, br, kc0, kc1);                 // 4 lgkm
        stage_A(Ab, 1, t2, Ah01, wave, r0, cb);
        VMW10; SB0; BAR; LGKM4; SB0;
        PRIO1; mfma16(acc, 1, 1, a1, b1); PRIO0;
        SB0; BAR;

        read_A(a1, Ah10, ar, kc0, kc1);                 // 8 lgkm
        stage_B(Wb, 1, t2, Bh01, wave, rB0, cb);
        VMW10; SB0; BAR; LGKM8; SB0;
        PRIO1; mfma16(acc, 0, 1, a0, b1); PRIO0;
        SB0; BAR;

        read_A(a0, Ah11, ar, kc0, kc1);                 // 8 lgkm
        stage_B(Wb, 0, t3, Bh10, wave, rB0, cb);
        VMW10; SB0; BAR; LGKM8; SB0;
        PRIO1; mfma16(acc, 0, 0, a1, b0); PRIO0;
        SB0; BAR;

        read_B(b1, Bh11, br, kc0, kc1);                 // 4 lgkm
        stage_A(Ab, 0, t3, Ah10, wave, r0, cb);
        VMW10; SB0; BAR; LGKM4; SB0;
        PRIO1; mfma16(acc, 1, 0, a0, b0); PRIO0;
        SB0; BAR;

        read_B(b0, Bh00, br, kc0, kc1);                 // 4 lgkm
        stage_A(Ab, 1, t3, Ah11, wave, r0, cb);
        VMW10; SB0; BAR; LGKM4; SB0;
        PRIO1; mfma16(acc, 1, 1, a0, b1); PRIO0;
        SB0; BAR;

        read_A(a0, Ah00, ar, kc0, kc1);                 // 8 lgkm
        stage_B(Wb, 1, t3, Bh11, wave, rB0, cb);
        VMW10; SB0; BAR; LGKM8; SB0;
        PRIO1; mfma16(acc, 0, 1, a1, b1); PRIO0;
        SB0; BAR;
    }

    // ---- fused cell epilogue: two 128-row passes through LDS ----
    VMW0; LGKM0;
    BAR;
    __hip_bfloat16* cl = (__hip_bfloat16*)lds;      // [128][256] bf16 = 64 KB
    const int h0 = bcol >> 2;
    #pragma unroll
    for (int p = 0; p < 2; ++p) {
        if (p) BAR;
        if (wr == p) {
            const int rb = ((lane >> 4) << 2);
            const int cbase = wc * 64 + (lane & 15);
            #pragma unroll
            for (int mi = 0; mi < 8; ++mi)
                #pragma unroll
                for (int ni = 0; ni < 4; ++ni)
                    #pragma unroll
                    for (int q = 0; q < 4; ++q)
                        cl[(rb + mi * 16 + q) * 256 + (cbase + ni * 16)] =
                            __float2bfloat16(acc[mi][ni][q]);
        }
        BAR;
        #pragma unroll
        for (int rnd = 0; rnd < 4; ++rnd) {
            const int row = rnd * 32 + (tid >> 4);
            const int ccol = (tid & 15) * 16;
            union { int4 q[2]; __hip_bfloat16 h[16]; } v;
            v.q[0] = *(const int4*)&cl[row * 256 + ccol];
            v.q[1] = *(const int4*)&cl[row * 256 + ccol + 8];
            const size_t R = (size_t)(brow + p * 128 + row);
            const int hh = h0 + (tid & 15) * 4;
            float4 cc = *(const float4*)(c + R * HDIM + hh);
            float cs[4] = {cc.x, cc.y, cc.z, cc.w};
            float ht[4];
            #pragma unroll
            for (int u = 0; u < 4; ++u) {
                float ft  = fsig(__bfloat162float(v.h[4 * u + 0]));
                float it  = fsig(__bfloat162float(v.h[4 * u + 1]));
                float ctt = fsig(__bfloat162float(v.h[4 * u + 2]));
                float ot  = fsig(__bfloat162float(v.h[4 * u + 3]));
                float ct  = ft * cs[u] + it * ctt;
                ht[u] = ot * ftanh(ct);
            }
            float4 o = {ht[0], ht[1], ht[2], ht[3]};
            *(float4*)(out + R * HDIM + hh) = o;
        }
    }
}

extern "C" void kernel_launch(void* const* d_in, const int* in_sizes, int n_in,
                              void* d_out, int out_size, void* d_ws, size_t ws_size,
                              hipStream_t stream) {
    const float* x    = (const float*)d_in[0];
    const float* prev = (const float*)d_in[1];
    const float* cst  = (const float*)d_in[2];
    const float* wfg  = (const float*)d_in[3];
    const float* wig  = (const float*)d_in[4];
    const float* wog  = (const float*)d_in[5];
    const float* wol  = (const float*)d_in[6];
    float* out = (float*)d_out;

    char* ws = (char*)d_ws;
    __hip_bfloat16* Abf = (__hip_bfloat16*)(ws);                 // 32 MB
    __hip_bfloat16* Wbf = (__hip_bfloat16*)(ws + 33554432);      // 64 MB

    k_concat_cast<<<2048, 256, 0, stream>>>(prev, x, Abf);
    k_cast_w<<<2048, 256, 0, stream>>>(wfg, wig, wog, wol, Wbf);
    k_gemm<<<512, 512, 0, stream>>>(Abf, Wbf, cst, out);
}

// Round 8
// 266.760 us; speedup vs baseline: 1.7765x; 1.0231x over previous
//
#include <hip/hip_runtime.h>
#include <hip/hip_bf16.h>
#include <cstdint>
#include <cstddef>

// ---------------------------------------------------------------------------
// LSTM cell: ht = sigmoid(o) * tanh(sigmoid(f)*c + sigmoid(i)*sigmoid(c~))
// gates = [prev_state, x] @ W'^T with W' row-interleaved: W'[4h+g] = W_g[h].
// Cell update fused into GEMM epilogue (gates never touch HBM).
// GEMM core: 256x256, BK=64, 8-region/2-K-tile schedule, ONE barrier per
// region: [reads(r); stage(r); vmcnt(10); lgkm(n_r); MFMA(r); BAR].
// lgkm(n_r) drains reads(r-1) only -> reads(r) overlap MFMA(r) on the LDS
// pipe. WAR chain: reads(r) drained at LGKM(r+1) < BAR(r+1) < stage(r+2).
// RAW chain: vmcnt(10)(r-1) < BAR(r-1) < reads(r) consuming stage(r-6).
// ---------------------------------------------------------------------------

typedef __bf16 nbf16;
typedef nbf16 bf16x8 __attribute__((ext_vector_type(8)));
typedef float f32x4 __attribute__((ext_vector_type(4)));

static constexpr int MDIM = 4096;
static constexpr int NDIM = 8192;
static constexpr int KDIM = 4096;
static constexpr int HDIM = 2048;
static constexpr int KB   = KDIM * 2;     // K row stride in bytes

#define VMW10 asm volatile("s_waitcnt vmcnt(10)" ::: "memory")
#define VMW0  asm volatile("s_waitcnt vmcnt(0)" ::: "memory")
#define LGKM0 asm volatile("s_waitcnt lgkmcnt(0)" ::: "memory")
#define LGKM4 asm volatile("s_waitcnt lgkmcnt(4)" ::: "memory")
#define LGKM8 asm volatile("s_waitcnt lgkmcnt(8)" ::: "memory")
#define BAR   __builtin_amdgcn_s_barrier()
#define SB0   __builtin_amdgcn_sched_barrier(0)
#define PRIO1 __builtin_amdgcn_s_setprio(1)
#define PRIO0 __builtin_amdgcn_s_setprio(0)

__device__ __forceinline__ void async16(void* lds, const void* g) {
    __builtin_amdgcn_global_load_lds(
        (const __attribute__((address_space(1))) void*)g,
        (__attribute__((address_space(3))) void*)lds,
        16, 0, 0);
}

__device__ __forceinline__ float fsig(float x) {
    return __builtin_amdgcn_rcpf(1.0f + __expf(-x));
}
__device__ __forceinline__ float ftanh(float x) {
    return 2.0f * __builtin_amdgcn_rcpf(1.0f + __expf(-2.0f * x)) - 1.0f;
}

// LDS half = 128 rows x 64 k bf16 = 16 KB; stored chunk = logical ^ (row&7),
// realized as linear LDS dest + inverse-permuted global source (rule 21).
__device__ __forceinline__ void stage_A(const char* Ab, int X, int t, char* slot,
                                        int wave, int r0, int cb) {
    const char* s = Ab + (size_t)(X * 64 + r0) * KB + t * 128 + cb;
    async16(slot + wave * 1024, s);
    async16(slot + (wave + 8) * 1024, s + (size_t)128 * KB);
}
__device__ __forceinline__ void stage_B(const char* Wb, int Y, int t, char* slot,
                                        int wave, int rB0, int cb) {
    const char* s = Wb + (size_t)(rB0 + Y * 32) * KB + t * 128 + cb;
    async16(slot + wave * 1024, s);
    async16(slot + (wave + 8) * 1024, s + (size_t)128 * KB);
}

__device__ __forceinline__ void read_A(bf16x8 (&d)[4][2], const char* hb,
                                       int ar, int kc0, int kc1) {
#pragma unroll
    for (int m = 0; m < 4; ++m) {
        d[m][0] = *(const bf16x8*)(hb + ar + m * 2048 + kc0);
        d[m][1] = *(const bf16x8*)(hb + ar + m * 2048 + kc1);
    }
}
__device__ __forceinline__ void read_B(bf16x8 (&d)[2][2], const char* hb,
                                       int br, int kc0, int kc1) {
#pragma unroll
    for (int j = 0; j < 2; ++j) {
        d[j][0] = *(const bf16x8*)(hb + br + j * 2048 + kc0);
        d[j][1] = *(const bf16x8*)(hb + br + j * 2048 + kc1);
    }
}
__device__ __forceinline__ void mfma16(f32x4 (&acc)[8][4], int mh, int Y,
                                       const bf16x8 (&a)[4][2],
                                       const bf16x8 (&b)[2][2]) {
#pragma unroll
    for (int m = 0; m < 4; ++m)
#pragma unroll
        for (int j = 0; j < 2; ++j) {
            acc[mh * 4 + m][Y * 2 + j] = __builtin_amdgcn_mfma_f32_16x16x32_bf16(
                a[m][0], b[j][0], acc[mh * 4 + m][Y * 2 + j], 0, 0, 0);
            acc[mh * 4 + m][Y * 2 + j] = __builtin_amdgcn_mfma_f32_16x16x32_bf16(
                a[m][1], b[j][1], acc[mh * 4 + m][Y * 2 + j], 0, 0, 0);
        }
}

// ---- concat(prev_state, x) -> bf16 A [MDIM][KDIM] -------------------------
__global__ __launch_bounds__(256) void k_concat_cast(
        const float* __restrict__ prev, const float* __restrict__ x,
        __hip_bfloat16* __restrict__ A) {
    const size_t total8 = (size_t)MDIM * KDIM / 8;
    const size_t stride = (size_t)gridDim.x * blockDim.x;
    for (size_t i = (size_t)blockIdx.x * blockDim.x + threadIdx.x; i < total8;
         i += stride) {
        size_t e = i * 8;
        size_t b = e >> 12;
        int k = (int)(e & (KDIM - 1));
        const float* src = (k < HDIM) ? (prev + b * HDIM + k)
                                      : (x + b * HDIM + (k - HDIM));
        float4 v0 = *(const float4*)src;
        float4 v1 = *(const float4*)(src + 4);
        union { __hip_bfloat16 h[8]; int4 q; } u;
        u.h[0] = __float2bfloat16(v0.x); u.h[1] = __float2bfloat16(v0.y);
        u.h[2] = __float2bfloat16(v0.z); u.h[3] = __float2bfloat16(v0.w);
        u.h[4] = __float2bfloat16(v1.x); u.h[5] = __float2bfloat16(v1.y);
        u.h[6] = __float2bfloat16(v1.z); u.h[7] = __float2bfloat16(v1.w);
        *(int4*)(A + e) = u.q;
    }
}

// ---- gate-interleaved W': row n = W_{n&3}[n>>2], bf16 [NDIM][KDIM] ---------
__global__ __launch_bounds__(256) void k_cast_w(
        const float* __restrict__ w0, const float* __restrict__ w1,
        const float* __restrict__ w2, const float* __restrict__ w3,
        __hip_bfloat16* __restrict__ W) {
    const size_t total8 = (size_t)NDIM * KDIM / 8;
    const size_t stride = (size_t)gridDim.x * blockDim.x;
    for (size_t i = (size_t)blockIdx.x * blockDim.x + threadIdx.x; i < total8;
         i += stride) {
        size_t e = i * 8;
        int n = (int)(e >> 12);
        int k = (int)(e & (KDIM - 1));
        int g = n & 3;
        size_t h = (size_t)(n >> 2);
        const float* src = (g == 0 ? w0 : g == 1 ? w1 : g == 2 ? w2 : w3)
                           + h * KDIM + k;
        float4 v0 = *(const float4*)src;
        float4 v1 = *(const float4*)(src + 4);
        union { __hip_bfloat16 h[8]; int4 q; } u;
        u.h[0] = __float2bfloat16(v0.x); u.h[1] = __float2bfloat16(v0.y);
        u.h[2] = __float2bfloat16(v0.z); u.h[3] = __float2bfloat16(v0.w);
        u.h[4] = __float2bfloat16(v1.x); u.h[5] = __float2bfloat16(v1.y);
        u.h[6] = __float2bfloat16(v1.z); u.h[7] = __float2bfloat16(v1.w);
        *(int4*)(W + e) = u.q;
    }
}

// ---- GEMM + fused LSTM cell epilogue ---------------------------------------
__global__ __launch_bounds__(512, 2) void k_gemm(
        const __hip_bfloat16* __restrict__ A, const __hip_bfloat16* __restrict__ W,
        const float* __restrict__ c, float* __restrict__ out) {
    __shared__ __align__(16) char lds[131072];

    // 2-D XCD swizzle: XCD (bid&7) owns an 8(mt) x 8(nt) sub-grid (bijective)
    const int bid = blockIdx.x;
    const int xcd = bid & 7, j = bid >> 3;
    const int mt = (xcd >> 2) * 8 + (j >> 3);
    const int nt = (xcd & 3) * 8 + (j & 7);
    const int brow = mt * 256, bcol = nt * 256;

    const int tid = threadIdx.x;
    const int wave = tid >> 6, lane = tid & 63;
    const int wr = wave >> 2, wc = wave & 3;

    const char* Ab = (const char*)A + (size_t)brow * KB;
    const char* Wb = (const char*)W + (size_t)bcol * KB;

    char* const Ah00 = lds;
    char* const Ah01 = lds + 16384;
    char* const Ah10 = lds + 32768;
    char* const Ah11 = lds + 49152;
    char* const Bh00 = lds + 65536;
    char* const Bh01 = lds + 81920;
    char* const Bh10 = lds + 98304;
    char* const Bh11 = lds + 114688;

    const int r0  = wave * 8 + (lane >> 3);
    const int rB0 = ((r0 >> 5) << 6) + (r0 & 31);
    const int cb  = (((lane & 7) ^ (lane >> 3)) << 4);
    const int kg  = lane >> 4;
    const int ar  = (wr * 64 + (lane & 15)) * 128;
    const int br  = (wc * 32 + (lane & 15)) * 128;
    const int kc0 = ((kg ^ (lane & 7)) << 4);
    const int kc1 = (((4 + kg) ^ (lane & 7)) << 4);

    f32x4 acc[8][4] = {};
    bf16x8 a0[4][2], a1[4][2], b0[2][2], b1[2][2];

    // ---- prologue: stage tiles 0 (s0) and 1 (s1) ----
    stage_B(Wb, 0, 0, Bh00, wave, rB0, cb);
    stage_A(Ab, 0, 0, Ah00, wave, r0, cb);
    stage_A(Ab, 1, 0, Ah01, wave, r0, cb);
    stage_B(Wb, 1, 0, Bh01, wave, rB0, cb);
    stage_B(Wb, 0, 1, Bh10, wave, rB0, cb);
    stage_A(Ab, 0, 1, Ah10, wave, r0, cb);
    stage_A(Ab, 1, 1, Ah11, wave, r0, cb);
    stage_B(Wb, 1, 1, Bh11, wave, rB0, cb);
    VMW10;                    // certify Bh00, Ah00, Ah01 (first 6 loads)
    SB0; BAR;
    read_A(a0, Ah00, ar, kc0, kc1);
    read_B(b0, Bh00, br, kc0, kc1);
    LGKM0;                    // drain pre-loop reads before ph1 restages Bh00
    SB0; BAR;

    // ---- main loop: 32 iterations x 2 K-tiles, ONE barrier per region ----
    for (int i = 0; i < 32; ++i) {
        const int t2 = (2 * i + 2) & 63;
        const int t3 = (2 * i + 3) & 63;

        // r1: reads A-hi(s0)->a1; stage B-lo(s0,t2); MFMA (mh0,Y0) [a0,b0]
        read_A(a1, Ah01, ar, kc0, kc1);
        stage_B(Wb, 0, t2, Bh00, wave, rB0, cb);
        VMW10; SB0; LGKM8; SB0;
        PRIO1; mfma16(acc, 0, 0, a0, b0); PRIO0;
        SB0; BAR;
        // r2: reads B-hi(s0)->b1; stage A-lo(s0,t2); MFMA (mh1,Y0) [a1,b0]
        read_B(b1, Bh01, br, kc0, kc1);
        stage_A(Ab, 0, t2, Ah00, wave, r0, cb);
        VMW10; SB0; LGKM4; SB0;
        PRIO1; mfma16(acc, 1, 0, a1, b0); PRIO0;
        SB0; BAR;
        // r3: reads B-lo(s1)->b0; stage A-hi(s0,t2); MFMA (mh1,Y1) [a1,b1]
        read_B(b0, Bh10, br, kc0, kc1);
        stage_A(Ab, 1, t2, Ah01, wave, r0, cb);
        VMW10; SB0; LGKM4; SB0;
        PRIO1; mfma16(acc, 1, 1, a1, b1); PRIO0;
        SB0; BAR;
        // r4: reads A-lo(s1)->a1; stage B-hi(s0,t2); MFMA (mh0,Y1) [a0,b1]
        read_A(a1, Ah10, ar, kc0, kc1);
        stage_B(Wb, 1, t2, Bh01, wave, rB0, cb);
        VMW10; SB0; LGKM8; SB0;
        PRIO1; mfma16(acc, 0, 1, a0, b1); PRIO0;
        SB0; BAR;
        // r5: reads A-hi(s1)->a0; stage B-lo(s1,t3); MFMA (mh0,Y0) [a1,b0]
        read_A(a0, Ah11, ar, kc0, kc1);
        stage_B(Wb, 0, t3, Bh10, wave, rB0, cb);
        VMW10; SB0; LGKM8; SB0;
        PRIO1; mfma16(acc, 0, 0, a1, b0); PRIO0;
        SB0; BAR;
        // r6: reads B-hi(s1)->b1; stage A-lo(s1,t3); MFMA (mh1,Y0) [a0,b0]
        read_B(b1, Bh11, br, kc0, kc1);
        stage_A(Ab, 0, t3, Ah10, wave, r0, cb);
        VMW10; SB0; LGKM4; SB0;
        PRIO1; mfma16(acc, 1, 0, a0, b0); PRIO0;
        SB0; BAR;
        // r7: reads B-lo(s0,t2)->b0; stage A-hi(s1,t3); MFMA (mh1,Y1) [a0,b1]
        read_B(b0, Bh00, br, kc0, kc1);
        stage_A(Ab, 1, t3, Ah11, wave, r0, cb);
        VMW10; SB0; LGKM4; SB0;
        PRIO1; mfma16(acc, 1, 1, a0, b1); PRIO0;
        SB0; BAR;
        // r8: reads A-lo(s0,t2)->a0; stage B-hi(s1,t3); MFMA (mh0,Y1) [a1,b1]
        read_A(a0, Ah00, ar, kc0, kc1);
        stage_B(Wb, 1, t3, Bh11, wave, rB0, cb);
        VMW10; SB0; LGKM8; SB0;
        PRIO1; mfma16(acc, 0, 1, a1, b1); PRIO0;
        SB0; BAR;
    }

    // ---- fused cell epilogue: two 128-row passes through LDS ----
    VMW0; LGKM0;
    BAR;
    __hip_bfloat16* cl = (__hip_bfloat16*)lds;      // [128][256] bf16 = 64 KB
    const int h0 = bcol >> 2;
    #pragma unroll
    for (int p = 0; p < 2; ++p) {
        if (p) BAR;
        if (wr == p) {
            const int rb = ((lane >> 4) << 2);
            const int cbase = wc * 64 + (lane & 15);
            #pragma unroll
            for (int mi = 0; mi < 8; ++mi)
                #pragma unroll
                for (int ni = 0; ni < 4; ++ni)
                    #pragma unroll
                    for (int q = 0; q < 4; ++q)
                        cl[(rb + mi * 16 + q) * 256 + (cbase + ni * 16)] =
                            __float2bfloat16(acc[mi][ni][q]);
        }
        BAR;
        #pragma unroll
        for (int rnd = 0; rnd < 4; ++rnd) {
            const int row = rnd * 32 + (tid >> 4);
            const int ccol = (tid & 15) * 16;
            union { int4 q[2]; __hip_bfloat16 h[16]; } v;
            v.q[0] = *(const int4*)&cl[row * 256 + ccol];
            v.q[1] = *(const int4*)&cl[row * 256 + ccol + 8];
            const size_t R = (size_t)(brow + p * 128 + row);
            const int hh = h0 + (tid & 15) * 4;
            float4 cc = *(const float4*)(c + R * HDIM + hh);
            float cs[4] = {cc.x, cc.y, cc.z, cc.w};
            float ht[4];
            #pragma unroll
            for (int u = 0; u < 4; ++u) {
                float ft  = fsig(__bfloat162float(v.h[4 * u + 0]));
                float it  = fsig(__bfloat162float(v.h[4 * u + 1]));
                float ctt = fsig(__bfloat162float(v.h[4 * u + 2]));
                float ot  = fsig(__bfloat162float(v.h[4 * u + 3]));
                float ct  = ft * cs[u] + it * ctt;
                ht[u] = ot * ftanh(ct);
            }
            float4 o = {ht[0], ht[1], ht[2], ht[3]};
            *(float4*)(out + R * HDIM + hh) = o;
        }
    }
}

extern "C" void kernel_launch(void* const* d_in, const int* in_sizes, int n_in,
                              void* d_out, int out_size, void* d_ws, size_t ws_size,
                              hipStream_t stream) {
    const float* x    = (const float*)d_in[0];
    const float* prev = (const float*)d_in[1];
    const float* cst  = (const float*)d_in[2];
    const float* wfg  = (const float*)d_in[3];
    const float* wig  = (const float*)d_in[4];
    const float* wog  = (const float*)d_in[5];
    const float* wol  = (const float*)d_in[6];
    float* out = (float*)d_out;

    char* ws = (char*)d_ws;
    __hip_bfloat16* Abf = (__hip_bfloat16*)(ws);                 // 32 MB
    __hip_bfloat16* Wbf = (__hip_bfloat16*)(ws + 33554432);      // 64 MB

    k_concat_cast<<<2048, 256, 0, stream>>>(prev, x, Abf);
    k_cast_w<<<2048, 256, 0, stream>>>(wfg, wig, wog, wol, Wbf);
    k_gemm<<<512, 512, 0, stream>>>(Abf, Wbf, cst, out);
}